// Round 3
// baseline (502.722 us; speedup 1.0000x reference)
//
#include <hip/hip_runtime.h>

// BlockPatchMasking: exact reproduction of the JAX reference.
// B=64, P=16384, F=3, MULTI_MASK=2 -> Bm=128 rows.
// num_centers=10, block_size=819, num_masks=9830.
//
// Verified round 1: the combinatorial result is bit-exact (absmax error was
// exactly float(1.0)-as-int32 minus 1 => every selected position matched the
// reference). Output must be written as int32 0/1 (bool ref -> int32 path).
//
// Arithmetic scheme for d2 (matches XLA-CPU bit-exactly, verified):
//   s2/q2: ((x*x + y*y) + z*z) plain rounds (XLA reduce, no FMA)
//   dot:   fma(a2,b2, fma(a1,b1, RN(a0*b0)))  (gemm FMA chain)
//   d2:    RN(RN(s2+q2) - RN(2*dot))
//
// (Round 2 was a GPUAcquisitionTimeout; this source is round 1 resubmitted.)

#define PP     16384
#define NBM    128
#define NC     10
#define KNN    819
#define NMASK  9830
#define NT     256
#define PER_T  64   // PP / NT

__device__ __forceinline__ unsigned mapf(float f) {
    unsigned u = __float_as_uint(f);
    return (u & 0x80000000u) ? ~u : (u | 0x80000000u);
}

// Exact k-th smallest (value,index) pair over keys[0..PP).
// Radix-select: 4x8-bit passes on value, 2x7-bit passes on index.
// All 256 threads participate. hist: 256 u32, sh: 8 u32 broadcast slots.
__device__ void select_kth(unsigned* keys, unsigned* hist, volatile unsigned* sh,
                           int k, unsigned& vstar, unsigned& pstar)
{
    const int t    = threadIdx.x;
    const int lane = t & 63;
    const int wv   = t >> 6;
    unsigned prefix = 0;
    int kk = k;

    for (int pass = 0; pass < 4; ++pass) {
        const int shift = 24 - pass * 8;
        hist[t] = 0;
        __syncthreads();
        for (int j = 0; j < PER_T; ++j) {
            const int p = j * NT + t;
            const unsigned v = keys[p];
            bool in;
            if (pass == 0) in = true;
            else           in = ((v >> (shift + 8)) == prefix);
            if (in) atomicAdd(&hist[(v >> shift) & 255u], 1u);
        }
        __syncthreads();
        int c = (int)hist[t];
        int x = c;
        #pragma unroll
        for (int off = 1; off < 64; off <<= 1) {
            int y = __shfl_up(x, off, 64);
            if (lane >= off) x += y;
        }
        if (lane == 63) sh[4 + wv] = (unsigned)x;
        __syncthreads();
        int base = 0;
        for (int w = 0; w < wv; ++w) base += (int)sh[4 + w];
        x += base;
        const int e = x - c;                 // exclusive cum before this bin
        if (e < kk && kk <= x) { sh[0] = (unsigned)t; sh[1] = (unsigned)(kk - e); }
        __syncthreads();
        prefix = (prefix << 8) | sh[0];
        kk = (int)sh[1];
        __syncthreads();
    }
    vstar = prefix;

    unsigned ipref = 0;
    for (int pass = 0; pass < 2; ++pass) {
        const int shift = 7 - pass * 7;
        hist[t] = 0;
        __syncthreads();
        for (int j = 0; j < PER_T; ++j) {
            const unsigned p = (unsigned)(j * NT + t);
            const unsigned v = keys[p];
            bool in = (v == vstar);
            if (in && pass != 0) in = ((p >> (shift + 7)) == ipref);
            if (in) atomicAdd(&hist[(p >> shift) & 127u], 1u);
        }
        __syncthreads();
        int c = (int)hist[t];
        int x = c;
        #pragma unroll
        for (int off = 1; off < 64; off <<= 1) {
            int y = __shfl_up(x, off, 64);
            if (lane >= off) x += y;
        }
        if (lane == 63) sh[4 + wv] = (unsigned)x;
        __syncthreads();
        int base = 0;
        for (int w = 0; w < wv; ++w) base += (int)sh[4 + w];
        x += base;
        const int e = x - c;
        if (e < kk && kk <= x) { sh[0] = (unsigned)t; sh[1] = (unsigned)(kk - e); }
        __syncthreads();
        ipref = (ipref << 7) | sh[0];
        kk = (int)sh[1];
        __syncthreads();
    }
    pstar = ipref;
}

__device__ __forceinline__ bool selected(unsigned v, unsigned p, unsigned vs, unsigned ps) {
    return (v < vs) || (v == vs && p <= ps);
}

extern "C" __global__ void __launch_bounds__(NT)
bpm_kernel(const float* __restrict__ centers,
           const float* __restrict__ rand_centers,
           const float* __restrict__ rand_mask,
           int* __restrict__ out)
{
    extern __shared__ unsigned smem[];
    unsigned* keys          = smem;                 // [PP]
    unsigned* hist          = smem + PP;            // [256]
    volatile unsigned* sh   = smem + PP + 256;      // [8]
    unsigned* clist         = smem + PP + 256 + 8;  // [16]
    unsigned* pcnt          = smem + PP + 256 + 8 + 16; // [1]

    const int bm = blockIdx.x;
    const int b  = bm >> 1;                          // repeat(centers,2,axis=0)
    const int t  = threadIdx.x;

    const float* crow  = centers      + (size_t)b  * PP * 3;
    const float* rcrow = rand_centers + (size_t)bm * PP;
    const float* rmrow = rand_mask    + (size_t)bm * PP;

    // ---- phase 1: 10 smallest (rand_centers, idx) -> block centers ----
    for (int j = 0; j < PER_T; ++j) {
        const int p = j * NT + t;
        keys[p] = mapf(rcrow[p]);
    }
    if (t == 0) *pcnt = 0;
    __syncthreads();
    unsigned vs, ps;
    select_kth(keys, hist, sh, NC, vs, ps);
    for (int j = 0; j < PER_T; ++j) {
        const int p = j * NT + t;
        if (selected(keys[p], (unsigned)p, vs, ps)) {
            unsigned pos = atomicAdd(pcnt, 1u);
            clist[pos] = (unsigned)p;               // order irrelevant (set union)
        }
    }
    __syncthreads();

    // ---- phase 2: union of 819-NN sets of the 10 centers ----
    unsigned long long um = 0ull;                   // bit j <-> point j*NT+t
    for (int c = 0; c < NC; ++c) {
        const int ci = (int)clist[c];
        const float sx = crow[ci * 3 + 0];
        const float sy = crow[ci * 3 + 1];
        const float sz = crow[ci * 3 + 2];
        const float s2 = __fadd_rn(__fadd_rn(__fmul_rn(sx, sx), __fmul_rn(sy, sy)),
                                   __fmul_rn(sz, sz));
        for (int j = 0; j < PER_T; ++j) {
            const int p = j * NT + t;
            const float* cp = crow + 3 * p;
            const float cx = cp[0], cy = cp[1], cz = cp[2];
            const float q2 = __fadd_rn(__fadd_rn(__fmul_rn(cx, cx), __fmul_rn(cy, cy)),
                                       __fmul_rn(cz, cz));
            float dot = __fmul_rn(sx, cx);
            dot = __fmaf_rn(sy, cy, dot);
            dot = __fmaf_rn(sz, cz, dot);
            const float d2 = __fsub_rn(__fadd_rn(s2, q2), __fmul_rn(2.0f, dot));
            keys[p] = mapf(d2);
        }
        __syncthreads();
        select_kth(keys, hist, sh, KNN, vs, ps);
        for (int j = 0; j < PER_T; ++j) {
            const int p = j * NT + t;
            if (selected(keys[p], (unsigned)p, vs, ps)) um |= (1ull << j);
        }
        __syncthreads();                             // keys reused next center
    }

    // ---- phase 3: 9830 smallest (flip, idx), flip = in_union ? -r : r ----
    for (int j = 0; j < PER_T; ++j) {
        const int p = j * NT + t;
        const float r = rmrow[p];
        const float f = ((um >> j) & 1ull) ? -r : r; // exact sign flip
        keys[p] = mapf(f);
    }
    __syncthreads();
    select_kth(keys, hist, sh, NMASK, vs, ps);
    int* orow = out + (size_t)bm * PP;
    for (int j = 0; j < PER_T; ++j) {
        const int p = j * NT + t;
        orow[p] = selected(keys[p], (unsigned)p, vs, ps) ? 1 : 0;
    }
}

extern "C" void kernel_launch(void* const* d_in, const int* in_sizes, int n_in,
                              void* d_out, int out_size, void* d_ws, size_t ws_size,
                              hipStream_t stream)
{
    const float* centers      = (const float*)d_in[0];
    const float* rand_centers = (const float*)d_in[1];
    const float* rand_mask    = (const float*)d_in[2];
    int* out = (int*)d_out;

    const size_t shmem = (size_t)(PP + 256 + 8 + 16 + 1) * sizeof(unsigned); // ~66 KiB
    // >64 KiB dynamic LDS needs the opt-in attribute (idempotent, graph-safe).
    hipFuncSetAttribute((const void*)bpm_kernel,
                        hipFuncAttributeMaxDynamicSharedMemorySize, (int)shmem);

    bpm_kernel<<<dim3(NBM), dim3(NT), shmem, stream>>>(centers, rand_centers, rand_mask, out);
}

// Round 4
// 230.037 us; speedup vs baseline: 2.1854x; 2.1854x over previous
//
#include <hip/hip_runtime.h>

// BlockPatchMasking — exact reproduction, parallelized.
// B=64,P=16384,F=3,MM=2 -> 128 rows. centers=10, knn=819, num_masks=9830.
// Round 3 verified bit-exact (absmax 0). This round: 3-kernel split for
// 10x phase-2 parallelism, NT=512, ballot-combined pass-0 histograms.
//
// d2 scheme (verified exact): s2/q2 = ((x*x+y*y)+z*z) plain RN;
// dot = fma(z, fma(y, mul(x))); d2 = RN(RN(s2+q2) - RN(2*dot)).

#define PP     16384
#define NROW   128
#define NC     10
#define KNN    819
#define NMASK  9830
#define NT     512
#define PER_T  (PP / NT)            // 32

#define UNI_WORDS_PER_ROW (PP / 32) // 512
#define WS_CL_U32   (NROW * 16)                    // clist region, u32s
#define WS_UNI_U32  (NROW * UNI_WORDS_PER_ROW)     // union bitmap, u32s
#define WS_NEED_BYTES ((size_t)(WS_CL_U32 + WS_UNI_U32) * 4)

#define SHM_U32   (PP + 256 + 8 + 24)
#define SHM_BYTES (SHM_U32 * 4)     // 66688 B

__device__ __forceinline__ unsigned mapf(float f) {
    unsigned u = __float_as_uint(f);
    return (u & 0x80000000u) ? ~u : (u | 0x80000000u);
}

// Exact k-th smallest (value,index) over keys[0..PP). 4x8-bit value passes
// (pass 0 uses wave ballot-combine: float keys are exponent-concentrated, a
// plain atomic histogram serializes ~50% of adds on one address), then
// 2x7-bit index passes (ties only -> sparse, plain atomics fine).
__device__ void select_kth(const unsigned* __restrict__ keys, unsigned* hist,
                           volatile unsigned* sh, int k,
                           unsigned& vstar, unsigned& pstar)
{
    const int t    = threadIdx.x;
    const int lane = t & 63;
    const int wv   = t >> 6;
    unsigned prefix = 0;
    int kk = k;

    for (int pass = 0; pass < 4; ++pass) {
        const int shift = 24 - pass * 8;
        if (t < 256) hist[t] = 0;
        __syncthreads();
        if (pass == 0) {
            for (int j = 0; j < PER_T; ++j) {
                const unsigned v = keys[j * NT + t];
                const unsigned bin = v >> 24;
                unsigned long long peers = ~0ull;
                #pragma unroll
                for (int bb = 0; bb < 8; ++bb) {
                    const unsigned long long m = __ballot((bin >> bb) & 1u);
                    peers &= ((bin >> bb) & 1u) ? m : ~m;
                }
                if (lane == __ffsll((unsigned long long)peers) - 1)
                    atomicAdd(&hist[bin], (unsigned)__popcll(peers));
            }
        } else {
            for (int j = 0; j < PER_T; ++j) {
                const unsigned v = keys[j * NT + t];
                if ((v >> (shift + 8)) == prefix)
                    atomicAdd(&hist[(v >> shift) & 255u], 1u);
            }
        }
        __syncthreads();
        int c = 0, x = 0;
        if (t < 256) {
            c = (int)hist[t]; x = c;
            #pragma unroll
            for (int off = 1; off < 64; off <<= 1) {
                const int y = __shfl_up(x, off, 64);
                if (lane >= off) x += y;
            }
            if (lane == 63) sh[4 + wv] = (unsigned)x;
        }
        __syncthreads();
        if (t < 256) {
            int base = 0;
            for (int w = 0; w < wv; ++w) base += (int)sh[4 + w];
            x += base;
            const int e = x - c;
            if (e < kk && kk <= x) { sh[0] = (unsigned)t; sh[1] = (unsigned)(kk - e); }
        }
        __syncthreads();
        prefix = (prefix << 8) | sh[0];
        kk = (int)sh[1];
        __syncthreads();
    }
    vstar = prefix;

    unsigned ipref = 0;
    for (int pass = 0; pass < 2; ++pass) {
        const int shift = 7 - pass * 7;
        if (t < 256) hist[t] = 0;
        __syncthreads();
        for (int j = 0; j < PER_T; ++j) {
            const unsigned p = (unsigned)(j * NT + t);
            const unsigned v = keys[p];
            bool in = (v == vstar);
            if (in && pass != 0) in = ((p >> (shift + 7)) == ipref);
            if (in) atomicAdd(&hist[(p >> shift) & 127u], 1u);
        }
        __syncthreads();
        int c = 0, x = 0;
        if (t < 256) {
            c = (int)hist[t]; x = c;
            #pragma unroll
            for (int off = 1; off < 64; off <<= 1) {
                const int y = __shfl_up(x, off, 64);
                if (lane >= off) x += y;
            }
            if (lane == 63) sh[4 + wv] = (unsigned)x;
        }
        __syncthreads();
        if (t < 256) {
            int base = 0;
            for (int w = 0; w < wv; ++w) base += (int)sh[4 + w];
            x += base;
            const int e = x - c;
            if (e < kk && kk <= x) { sh[0] = (unsigned)t; sh[1] = (unsigned)(kk - e); }
        }
        __syncthreads();
        ipref = (ipref << 7) | sh[0];
        kk = (int)sh[1];
        __syncthreads();
    }
    pstar = ipref;
}

__device__ __forceinline__ bool selected(unsigned v, unsigned p, unsigned vs, unsigned ps) {
    return (v < vs) || (v == vs && p <= ps);
}

__device__ __forceinline__ float d2_exact(float sx, float sy, float sz, float s2,
                                          const float* __restrict__ cp)
{
    const float cx = cp[0], cy = cp[1], cz = cp[2];
    const float q2 = __fadd_rn(__fadd_rn(__fmul_rn(cx, cx), __fmul_rn(cy, cy)),
                               __fmul_rn(cz, cz));
    float dot = __fmul_rn(sx, cx);
    dot = __fmaf_rn(sy, cy, dot);
    dot = __fmaf_rn(sz, cz, dot);
    return __fsub_rn(__fadd_rn(s2, q2), __fmul_rn(2.0f, dot));
}

// ---- kernel A: 10 smallest rand_centers per row -> ws clist ----
extern "C" __global__ void __launch_bounds__(NT, 4)
bpm_centers(const float* __restrict__ rand_centers, unsigned* __restrict__ ws_cl)
{
    extern __shared__ unsigned smem[];
    unsigned* keys = smem;
    unsigned* hist = smem + PP;
    volatile unsigned* sh = smem + PP + 256;
    unsigned* clist = smem + PP + 264;      // 16
    unsigned* pcnt  = smem + PP + 280;      // 1

    const int bm = blockIdx.x;
    const int t  = threadIdx.x;
    const float* rcrow = rand_centers + (size_t)bm * PP;

    for (int j = 0; j < PER_T; ++j) {
        const int p = j * NT + t;
        keys[p] = mapf(rcrow[p]);
    }
    if (t == 0) *pcnt = 0;
    __syncthreads();
    unsigned vs, ps;
    select_kth(keys, hist, sh, NC, vs, ps);
    for (int j = 0; j < PER_T; ++j) {
        const int p = j * NT + t;
        if (selected(keys[p], (unsigned)p, vs, ps))
            clist[atomicAdd(pcnt, 1u)] = (unsigned)p;   // order irrelevant
    }
    __syncthreads();
    if (t < NC) ws_cl[bm * 16 + t] = clist[t];
}

// ---- kernel B: one block per (row, center): 819-NN -> atomicOr bitmap ----
extern "C" __global__ void __launch_bounds__(NT, 4)
bpm_knn(const float* __restrict__ centers, const unsigned* __restrict__ ws_cl,
        unsigned* __restrict__ uni)
{
    extern __shared__ unsigned smem[];
    unsigned* keys = smem;
    unsigned* hist = smem + PP;
    volatile unsigned* sh = smem + PP + 256;

    const int c  = blockIdx.x;
    const int bm = blockIdx.y;
    const int b  = bm >> 1;
    const int t  = threadIdx.x;
    const float* crow = centers + (size_t)b * PP * 3;

    const int ci = (int)ws_cl[bm * 16 + c];
    const float sx = crow[ci * 3 + 0];
    const float sy = crow[ci * 3 + 1];
    const float sz = crow[ci * 3 + 2];
    const float s2 = __fadd_rn(__fadd_rn(__fmul_rn(sx, sx), __fmul_rn(sy, sy)),
                               __fmul_rn(sz, sz));
    for (int j = 0; j < PER_T; ++j) {
        const int p = j * NT + t;
        keys[p] = mapf(d2_exact(sx, sy, sz, s2, crow + 3 * p));
    }
    __syncthreads();
    unsigned vs, ps;
    select_kth(keys, hist, sh, KNN, vs, ps);

    unsigned* urow = uni + (size_t)bm * UNI_WORDS_PER_ROW;
    for (int j = 0; j < PER_T; ++j) {
        const int p = j * NT + t;
        const bool sel = selected(keys[p], (unsigned)p, vs, ps);
        const unsigned long long bmask = __ballot(sel);
        if ((t & 63) == 0 && bmask) {
            const int wbase = (j * NT + (t >> 6) * 64) >> 5;
            const unsigned lo = (unsigned)bmask;
            const unsigned hi = (unsigned)(bmask >> 32);
            if (lo) atomicOr(&urow[wbase], lo);
            if (hi) atomicOr(&urow[wbase + 1], hi);
        }
    }
}

// ---- kernel C: flip by union bit, select 9830, write int mask ----
extern "C" __global__ void __launch_bounds__(NT, 4)
bpm_final(const float* __restrict__ rand_mask, const unsigned* __restrict__ uni,
          int* __restrict__ out)
{
    extern __shared__ unsigned smem[];
    unsigned* keys = smem;
    unsigned* hist = smem + PP;
    volatile unsigned* sh = smem + PP + 256;

    const int bm = blockIdx.x;
    const int t  = threadIdx.x;
    const float* rmrow = rand_mask + (size_t)bm * PP;
    const unsigned* urow = uni + (size_t)bm * UNI_WORDS_PER_ROW;

    for (int j = 0; j < PER_T; ++j) {
        const int p = j * NT + t;
        const float r = rmrow[p];
        const bool inb = (urow[p >> 5] >> (p & 31)) & 1u;
        keys[p] = mapf(inb ? -r : r);
    }
    __syncthreads();
    unsigned vs, ps;
    select_kth(keys, hist, sh, NMASK, vs, ps);
    int* orow = out + (size_t)bm * PP;
    for (int j = 0; j < PER_T; ++j) {
        const int p = j * NT + t;
        orow[p] = selected(keys[p], (unsigned)p, vs, ps) ? 1 : 0;
    }
}

// ---- fallback: monolithic (used only if d_ws is too small) ----
extern "C" __global__ void __launch_bounds__(NT, 4)
bpm_mono(const float* __restrict__ centers, const float* __restrict__ rand_centers,
         const float* __restrict__ rand_mask, int* __restrict__ out)
{
    extern __shared__ unsigned smem[];
    unsigned* keys = smem;
    unsigned* hist = smem + PP;
    volatile unsigned* sh = smem + PP + 256;
    unsigned* clist = smem + PP + 264;
    unsigned* pcnt  = smem + PP + 280;

    const int bm = blockIdx.x;
    const int b  = bm >> 1;
    const int t  = threadIdx.x;
    const float* crow  = centers      + (size_t)b  * PP * 3;
    const float* rcrow = rand_centers + (size_t)bm * PP;
    const float* rmrow = rand_mask    + (size_t)bm * PP;

    for (int j = 0; j < PER_T; ++j) keys[j * NT + t] = mapf(rcrow[j * NT + t]);
    if (t == 0) *pcnt = 0;
    __syncthreads();
    unsigned vs, ps;
    select_kth(keys, hist, sh, NC, vs, ps);
    for (int j = 0; j < PER_T; ++j) {
        const int p = j * NT + t;
        if (selected(keys[p], (unsigned)p, vs, ps))
            clist[atomicAdd(pcnt, 1u)] = (unsigned)p;
    }
    __syncthreads();

    unsigned um = 0;
    for (int c = 0; c < NC; ++c) {
        const int ci = (int)clist[c];
        const float sx = crow[ci * 3 + 0];
        const float sy = crow[ci * 3 + 1];
        const float sz = crow[ci * 3 + 2];
        const float s2 = __fadd_rn(__fadd_rn(__fmul_rn(sx, sx), __fmul_rn(sy, sy)),
                                   __fmul_rn(sz, sz));
        for (int j = 0; j < PER_T; ++j) {
            const int p = j * NT + t;
            keys[p] = mapf(d2_exact(sx, sy, sz, s2, crow + 3 * p));
        }
        __syncthreads();
        select_kth(keys, hist, sh, KNN, vs, ps);
        for (int j = 0; j < PER_T; ++j) {
            const int p = j * NT + t;
            if (selected(keys[p], (unsigned)p, vs, ps)) um |= (1u << j);
        }
        __syncthreads();
    }

    for (int j = 0; j < PER_T; ++j) {
        const int p = j * NT + t;
        const float r = rmrow[p];
        keys[p] = mapf(((um >> j) & 1u) ? -r : r);
    }
    __syncthreads();
    select_kth(keys, hist, sh, NMASK, vs, ps);
    int* orow = out + (size_t)bm * PP;
    for (int j = 0; j < PER_T; ++j) {
        const int p = j * NT + t;
        orow[p] = selected(keys[p], (unsigned)p, vs, ps) ? 1 : 0;
    }
}

extern "C" void kernel_launch(void* const* d_in, const int* in_sizes, int n_in,
                              void* d_out, int out_size, void* d_ws, size_t ws_size,
                              hipStream_t stream)
{
    (void)in_sizes; (void)n_in; (void)out_size;
    const float* centers      = (const float*)d_in[0];
    const float* rand_centers = (const float*)d_in[1];
    const float* rand_mask    = (const float*)d_in[2];
    int* out = (int*)d_out;

    hipFuncSetAttribute((const void*)bpm_centers,
                        hipFuncAttributeMaxDynamicSharedMemorySize, SHM_BYTES);
    hipFuncSetAttribute((const void*)bpm_knn,
                        hipFuncAttributeMaxDynamicSharedMemorySize, SHM_BYTES);
    hipFuncSetAttribute((const void*)bpm_final,
                        hipFuncAttributeMaxDynamicSharedMemorySize, SHM_BYTES);
    hipFuncSetAttribute((const void*)bpm_mono,
                        hipFuncAttributeMaxDynamicSharedMemorySize, SHM_BYTES);

    if (ws_size >= WS_NEED_BYTES) {
        unsigned* ws_cl = (unsigned*)d_ws;
        unsigned* uni   = ws_cl + WS_CL_U32;
        hipMemsetAsync(uni, 0, (size_t)WS_UNI_U32 * 4, stream);   // ws is poisoned
        bpm_centers<<<dim3(NROW), dim3(NT), SHM_BYTES, stream>>>(rand_centers, ws_cl);
        bpm_knn<<<dim3(NC, NROW), dim3(NT), SHM_BYTES, stream>>>(centers, ws_cl, uni);
        bpm_final<<<dim3(NROW), dim3(NT), SHM_BYTES, stream>>>(rand_mask, uni, out);
    } else {
        bpm_mono<<<dim3(NROW), dim3(NT), SHM_BYTES, stream>>>(centers, rand_centers,
                                                              rand_mask, out);
    }
}

// Round 5
// 216.313 us; speedup vs baseline: 2.3241x; 1.0634x over previous
//
#include <hip/hip_runtime.h>

// BlockPatchMasking — exact reproduction, round 5: candidate-compaction select.
// B=64,P=16384,F=3,MM=2 -> 128 rows. centers=10, knn=819, num_masks=9830.
// Bit-exact verified (rounds 3,4: absmax 0). d2 scheme (verified exact):
//   s2/q2 = ((x*x+y*y)+z*z) plain RN; dot = fma chain; d2 = RN(RN(s2+q2)-RN(2*dot))
//
// select_kth_fast: pass0 8-bit ballot histogram -> compact hot-bin candidates
// (u16 idx list, CAP 7168) -> per-list 8-bit passes -> <=64 candidates ->
// single-wave (value,index) rank select. Overflow -> verified full 6-pass path.

#define PP     16384
#define NROW   128
#define NC     10
#define KNN    819
#define NMASK  9830
#define NT     512
#define PER_T  (PP / NT)            // 32
#define CAP    7168
#define CPT    (CAP / NT)           // 14 candidates staged per thread

#define UNI_WORDS_PER_ROW (PP / 32) // 512
#define WS_CL_U32   (NROW * 16)
#define WS_UNI_U32  (NROW * UNI_WORDS_PER_ROW)     // 65536 == NROW*NT
#define WS_NEED_BYTES ((size_t)(WS_CL_U32 + WS_UNI_U32) * 4)

// u32 offsets in dynamic LDS
#define OFF_HIST  PP
#define OFF_SH    (PP + 256)
#define OFF_CCNT  (PP + 280)
#define OFF_CLIST (PP + 281)
#define OFF_PCNT  (PP + 297)
#define OFF_CAND  (PP + 298)
#define SHM_BYTES ((OFF_CAND) * 4 + CAP * 2)       // 81064 B -> 2 blocks/CU

__device__ __forceinline__ unsigned mapf(float f) {
    unsigned u = __float_as_uint(f);
    return (u & 0x80000000u) ? ~u : (u | 0x80000000u);
}

__device__ __forceinline__ bool selected(unsigned v, unsigned p, unsigned vs, unsigned ps) {
    return (v < vs) || (v == vs && p <= ps);
}

// Find bin whose cumulative count crosses kk. hist[0..nbins) valid.
// Returns bin in *bin_out, updates *kk_io to rank within that bin. Uniform.
__device__ void hist_pick(unsigned* hist, volatile unsigned* sh, int nbins,
                          int* kk_io, unsigned* bin_out)
{
    const int t = threadIdx.x, lane = t & 63, wv = t >> 6;
    const int kk = *kk_io;
    int c = 0, x = 0;
    if (t < nbins) {
        c = (int)hist[t]; x = c;
        #pragma unroll
        for (int off = 1; off < 64; off <<= 1) {
            const int y = __shfl_up(x, off, 64);
            if (lane >= off) x += y;
        }
        if (lane == 63) sh[4 + wv] = (unsigned)x;
    }
    __syncthreads();
    if (t < nbins) {
        int base = 0;
        for (int w = 0; w < wv; ++w) base += (int)sh[4 + w];
        x += base;
        const int e = x - c;
        if (e < kk && kk <= x) { sh[0] = (unsigned)t; sh[1] = (unsigned)(kk - e); }
    }
    __syncthreads();
    *bin_out = sh[0];
    *kk_io = (int)sh[1];
    __syncthreads();
}

// Verified full 6-pass radix select (round-4 path). Fallback for CAP overflow.
__device__ void select_kth_full(const unsigned* __restrict__ keys, unsigned* hist,
                                volatile unsigned* sh, int k,
                                unsigned& vstar, unsigned& pstar)
{
    const int t = threadIdx.x, lane = t & 63;
    unsigned prefix = 0;
    int kk = k;

    for (int pass = 0; pass < 4; ++pass) {
        const int shift = 24 - pass * 8;
        if (t < 256) hist[t] = 0;
        __syncthreads();
        if (pass == 0) {
            for (int j = 0; j < PER_T; ++j) {
                const unsigned v = keys[j * NT + t];
                const unsigned bin = v >> 24;
                unsigned long long peers = ~0ull;
                #pragma unroll
                for (int bb = 0; bb < 8; ++bb) {
                    const unsigned long long m = __ballot((bin >> bb) & 1u);
                    peers &= ((bin >> bb) & 1u) ? m : ~m;
                }
                if (lane == __ffsll((unsigned long long)peers) - 1)
                    atomicAdd(&hist[bin], (unsigned)__popcll(peers));
            }
        } else {
            for (int j = 0; j < PER_T; ++j) {
                const unsigned v = keys[j * NT + t];
                if ((v >> (shift + 8)) == prefix)
                    atomicAdd(&hist[(v >> shift) & 255u], 1u);
            }
        }
        __syncthreads();
        unsigned b;
        hist_pick(hist, sh, 256, &kk, &b);
        prefix = (prefix << 8) | b;
    }
    vstar = prefix;

    unsigned ipref = 0;
    for (int pass = 0; pass < 2; ++pass) {
        const int shift = 7 - pass * 7;
        if (t < 256) hist[t] = 0;
        __syncthreads();
        for (int j = 0; j < PER_T; ++j) {
            const unsigned p = (unsigned)(j * NT + t);
            const unsigned v = keys[p];
            bool in = (v == vstar);
            if (in && pass != 0) in = ((p >> (shift + 7)) == ipref);
            if (in) atomicAdd(&hist[(p >> shift) & 127u], 1u);
        }
        __syncthreads();
        unsigned b;
        hist_pick(hist, sh, 128, &kk, &b);
        ipref = (ipref << 7) | b;
    }
    pstar = ipref;
}

// Fast exact select via candidate compaction.
__device__ void select_kth_fast(const unsigned* __restrict__ keys, unsigned* hist,
                                volatile unsigned* sh, unsigned short* cand,
                                unsigned* ccnt, int k,
                                unsigned& vstar, unsigned& pstar)
{
    const int t = threadIdx.x, lane = t & 63;
    int kk = k;

    // pass 0: 8-bit ballot-combined histogram over all keys
    if (t < 256) hist[t] = 0;
    __syncthreads();
    for (int j = 0; j < PER_T; ++j) {
        const unsigned v = keys[j * NT + t];
        const unsigned bin = v >> 24;
        unsigned long long peers = ~0ull;
        #pragma unroll
        for (int bb = 0; bb < 8; ++bb) {
            const unsigned long long m = __ballot((bin >> bb) & 1u);
            peers &= ((bin >> bb) & 1u) ? m : ~m;
        }
        if (lane == __ffsll((unsigned long long)peers) - 1)
            atomicAdd(&hist[bin], (unsigned)__popcll(peers));
    }
    __syncthreads();
    unsigned b0;
    hist_pick(hist, sh, 256, &kk, &b0);
    unsigned prefix = b0;

    // compact candidates (byte3 == b0) into u16 index list
    if (t == 0) *ccnt = 0;
    __syncthreads();
    for (int j = 0; j < PER_T; ++j) {
        const int p = j * NT + t;
        if ((keys[p] >> 24) == b0) {
            const unsigned pos = atomicAdd(ccnt, 1u);
            if (pos < CAP) cand[pos] = (unsigned short)p;
        }
    }
    __syncthreads();
    unsigned C = *ccnt;
    __syncthreads();
    if (C > CAP) {                       // rare adversarial bin -> exact fallback
        select_kth_full(keys, hist, sh, k, vstar, pstar);
        return;
    }

    // narrow by bytes 2,1,0 over the candidate list
    int level = 1;
    while (C > 64u && level < 4) {
        const int shift = 24 - level * 8;
        if (t < 256) hist[t] = 0;
        __syncthreads();
        unsigned ci[CPT]; unsigned kb[CPT]; bool va[CPT];
        #pragma unroll
        for (int i = 0; i < CPT; ++i) {
            const unsigned pos = (unsigned)(i * NT + t);
            va[i] = pos < C;
            ci[i] = va[i] ? (unsigned)cand[pos] : 0u;
            kb[i] = va[i] ? ((keys[ci[i]] >> shift) & 255u) : 0u;
            if (va[i]) atomicAdd(&hist[kb[i]], 1u);
        }
        __syncthreads();
        unsigned bl;
        hist_pick(hist, sh, 256, &kk, &bl);
        prefix = (prefix << 8) | bl;
        if (t == 0) *ccnt = 0;
        __syncthreads();
        #pragma unroll
        for (int i = 0; i < CPT; ++i)
            if (va[i] && kb[i] == bl)
                cand[atomicAdd(ccnt, 1u)] = (unsigned short)ci[i];
        __syncthreads();
        C = *ccnt;
        __syncthreads();
        ++level;
    }

    if (C <= 64u) {
        // single-wave exact rank select over (value, index) pairs
        if (t < 64) {
            unsigned v = 0xFFFFFFFFu, pidx = 0xFFFFu;
            if ((unsigned)t < C) { pidx = (unsigned)cand[t]; v = keys[pidx]; }
            int rank = 0;
            for (unsigned j = 0; j < C; ++j) {
                const unsigned vj = __shfl(v, (int)j, 64);
                const unsigned pj = __shfl(pidx, (int)j, 64);
                if (vj < v || (vj == v && pj < pidx)) ++rank;
            }
            if ((unsigned)t < C && rank == kk - 1) { sh[0] = v; sh[1] = pidx; }
        }
        __syncthreads();
        vstar = sh[0];
        pstar = sh[1];
        __syncthreads();
        return;
    }

    // >64 full-value ties: all candidates share value == prefix
    vstar = prefix;
    {   // 7-bit index pass over tie list
        if (t < 256) hist[t] = 0;
        __syncthreads();
        unsigned ci[CPT]; bool va[CPT];
        #pragma unroll
        for (int i = 0; i < CPT; ++i) {
            const unsigned pos = (unsigned)(i * NT + t);
            va[i] = pos < C;
            ci[i] = va[i] ? (unsigned)cand[pos] : 0u;
            if (va[i]) atomicAdd(&hist[ci[i] >> 7], 1u);
        }
        __syncthreads();
        unsigned bl;
        hist_pick(hist, sh, 128, &kk, &bl);
        if (t == 0) *ccnt = 0;
        __syncthreads();
        #pragma unroll
        for (int i = 0; i < CPT; ++i)
            if (va[i] && (ci[i] >> 7) == bl)
                cand[atomicAdd(ccnt, 1u)] = (unsigned short)ci[i];
        __syncthreads();
        C = *ccnt;                       // <= 128
        __syncthreads();
    }
    if (t < 64) {
        unsigned p0 = 0xFFFFu, p1 = 0xFFFFu;
        if ((unsigned)t < C)        p0 = (unsigned)cand[t];
        if ((unsigned)(t + 64) < C) p1 = (unsigned)cand[t + 64];
        int r0 = 0, r1 = 0;
        for (unsigned j = 0; j < C; ++j) {
            const unsigned pj = (j < 64) ? __shfl(p0, (int)j, 64)
                                         : __shfl(p1, (int)(j - 64), 64);
            if (pj < p0) ++r0;
            if (pj < p1) ++r1;
        }
        if ((unsigned)t < C && r0 == kk - 1)        sh[1] = p0;
        if ((unsigned)(t + 64) < C && r1 == kk - 1) sh[1] = p1;
    }
    __syncthreads();
    pstar = sh[1];
    __syncthreads();
}

__device__ __forceinline__ float d2_exact(float sx, float sy, float sz, float s2,
                                          const float* __restrict__ cp)
{
    const float cx = cp[0], cy = cp[1], cz = cp[2];
    const float q2 = __fadd_rn(__fadd_rn(__fmul_rn(cx, cx), __fmul_rn(cy, cy)),
                               __fmul_rn(cz, cz));
    float dot = __fmul_rn(sx, cx);
    dot = __fmaf_rn(sy, cy, dot);
    dot = __fmaf_rn(sz, cz, dot);
    return __fsub_rn(__fadd_rn(s2, q2), __fmul_rn(2.0f, dot));
}

// ---- kernel A: 10 smallest rand_centers per row; also clears union bitmap ----
extern "C" __global__ void __launch_bounds__(NT, 4)
bpm_centers(const float* __restrict__ rand_centers, unsigned* __restrict__ ws_cl,
            unsigned* __restrict__ uni)
{
    extern __shared__ unsigned smem[];
    unsigned* keys = smem;
    unsigned* hist = smem + OFF_HIST;
    volatile unsigned* sh = smem + OFF_SH;
    unsigned* ccnt = smem + OFF_CCNT;
    unsigned* clist = smem + OFF_CLIST;
    unsigned* pcnt = smem + OFF_PCNT;
    unsigned short* cand = (unsigned short*)(smem + OFF_CAND);

    const int bm = blockIdx.x;
    const int t  = threadIdx.x;
    uni[bm * NT + t] = 0u;                       // clear union bitmap (65536 words)

    const float* rcrow = rand_centers + (size_t)bm * PP;
    for (int j = 0; j < PER_T; ++j) {
        const int p = j * NT + t;
        keys[p] = mapf(rcrow[p]);
    }
    if (t == 0) *pcnt = 0;
    __syncthreads();
    unsigned vs, ps;
    select_kth_fast(keys, hist, sh, cand, ccnt, NC, vs, ps);
    for (int j = 0; j < PER_T; ++j) {
        const int p = j * NT + t;
        if (selected(keys[p], (unsigned)p, vs, ps))
            clist[atomicAdd(pcnt, 1u)] = (unsigned)p;   // order irrelevant (union)
    }
    __syncthreads();
    if (t < NC) ws_cl[bm * 16 + t] = clist[t];
}

// ---- kernel B: one block per (row, center): 819-NN -> atomicOr bitmap ----
extern "C" __global__ void __launch_bounds__(NT, 4)
bpm_knn(const float* __restrict__ centers, const unsigned* __restrict__ ws_cl,
        unsigned* __restrict__ uni)
{
    extern __shared__ unsigned smem[];
    unsigned* keys = smem;
    unsigned* hist = smem + OFF_HIST;
    volatile unsigned* sh = smem + OFF_SH;
    unsigned* ccnt = smem + OFF_CCNT;
    unsigned short* cand = (unsigned short*)(smem + OFF_CAND);

    const int c  = blockIdx.x;
    const int bm = blockIdx.y;
    const int b  = bm >> 1;
    const int t  = threadIdx.x;
    const float* crow = centers + (size_t)b * PP * 3;

    const int ci = (int)ws_cl[bm * 16 + c];
    const float sx = crow[ci * 3 + 0];
    const float sy = crow[ci * 3 + 1];
    const float sz = crow[ci * 3 + 2];
    const float s2 = __fadd_rn(__fadd_rn(__fmul_rn(sx, sx), __fmul_rn(sy, sy)),
                               __fmul_rn(sz, sz));
    for (int j = 0; j < PER_T; ++j) {
        const int p = j * NT + t;
        keys[p] = mapf(d2_exact(sx, sy, sz, s2, crow + 3 * p));
    }
    __syncthreads();
    unsigned vs, ps;
    select_kth_fast(keys, hist, sh, cand, ccnt, KNN, vs, ps);

    unsigned* urow = uni + (size_t)bm * UNI_WORDS_PER_ROW;
    for (int j = 0; j < PER_T; ++j) {
        const int p = j * NT + t;
        const bool sel = selected(keys[p], (unsigned)p, vs, ps);
        const unsigned long long bmask = __ballot(sel);
        if ((t & 63) == 0 && bmask) {
            const int wbase = (j * NT + (t >> 6) * 64) >> 5;
            const unsigned lo = (unsigned)bmask;
            const unsigned hi = (unsigned)(bmask >> 32);
            if (lo) atomicOr(&urow[wbase], lo);
            if (hi) atomicOr(&urow[wbase + 1], hi);
        }
    }
}

// ---- kernel C: flip by union bit, select 9830, write int mask ----
extern "C" __global__ void __launch_bounds__(NT, 4)
bpm_final(const float* __restrict__ rand_mask, const unsigned* __restrict__ uni,
          int* __restrict__ out)
{
    extern __shared__ unsigned smem[];
    unsigned* keys = smem;
    unsigned* hist = smem + OFF_HIST;
    volatile unsigned* sh = smem + OFF_SH;
    unsigned* ccnt = smem + OFF_CCNT;
    unsigned short* cand = (unsigned short*)(smem + OFF_CAND);

    const int bm = blockIdx.x;
    const int t  = threadIdx.x;
    const float* rmrow = rand_mask + (size_t)bm * PP;
    const unsigned* urow = uni + (size_t)bm * UNI_WORDS_PER_ROW;

    for (int j = 0; j < PER_T; ++j) {
        const int p = j * NT + t;
        const float r = rmrow[p];
        const bool inb = (urow[p >> 5] >> (p & 31)) & 1u;
        keys[p] = mapf(inb ? -r : r);
    }
    __syncthreads();
    unsigned vs, ps;
    select_kth_fast(keys, hist, sh, cand, ccnt, NMASK, vs, ps);
    int* orow = out + (size_t)bm * PP;
    for (int j = 0; j < PER_T; ++j) {
        const int p = j * NT + t;
        orow[p] = selected(keys[p], (unsigned)p, vs, ps) ? 1 : 0;
    }
}

// ---- fallback: monolithic (used only if d_ws is too small) ----
extern "C" __global__ void __launch_bounds__(NT, 4)
bpm_mono(const float* __restrict__ centers, const float* __restrict__ rand_centers,
         const float* __restrict__ rand_mask, int* __restrict__ out)
{
    extern __shared__ unsigned smem[];
    unsigned* keys = smem;
    unsigned* hist = smem + OFF_HIST;
    volatile unsigned* sh = smem + OFF_SH;
    unsigned* ccnt = smem + OFF_CCNT;
    unsigned* clist = smem + OFF_CLIST;
    unsigned* pcnt = smem + OFF_PCNT;
    unsigned short* cand = (unsigned short*)(smem + OFF_CAND);

    const int bm = blockIdx.x;
    const int b  = bm >> 1;
    const int t  = threadIdx.x;
    const float* crow  = centers      + (size_t)b  * PP * 3;
    const float* rcrow = rand_centers + (size_t)bm * PP;
    const float* rmrow = rand_mask    + (size_t)bm * PP;

    for (int j = 0; j < PER_T; ++j) keys[j * NT + t] = mapf(rcrow[j * NT + t]);
    if (t == 0) *pcnt = 0;
    __syncthreads();
    unsigned vs, ps;
    select_kth_fast(keys, hist, sh, cand, ccnt, NC, vs, ps);
    for (int j = 0; j < PER_T; ++j) {
        const int p = j * NT + t;
        if (selected(keys[p], (unsigned)p, vs, ps))
            clist[atomicAdd(pcnt, 1u)] = (unsigned)p;
    }
    __syncthreads();

    unsigned um = 0;
    for (int c = 0; c < NC; ++c) {
        const int ci = (int)clist[c];
        const float sx = crow[ci * 3 + 0];
        const float sy = crow[ci * 3 + 1];
        const float sz = crow[ci * 3 + 2];
        const float s2 = __fadd_rn(__fadd_rn(__fmul_rn(sx, sx), __fmul_rn(sy, sy)),
                                   __fmul_rn(sz, sz));
        for (int j = 0; j < PER_T; ++j) {
            const int p = j * NT + t;
            keys[p] = mapf(d2_exact(sx, sy, sz, s2, crow + 3 * p));
        }
        __syncthreads();
        select_kth_fast(keys, hist, sh, cand, ccnt, KNN, vs, ps);
        for (int j = 0; j < PER_T; ++j) {
            const int p = j * NT + t;
            if (selected(keys[p], (unsigned)p, vs, ps)) um |= (1u << j);
        }
        __syncthreads();
    }

    for (int j = 0; j < PER_T; ++j) {
        const int p = j * NT + t;
        const float r = rmrow[p];
        keys[p] = mapf(((um >> j) & 1u) ? -r : r);
    }
    __syncthreads();
    select_kth_fast(keys, hist, sh, cand, ccnt, NMASK, vs, ps);
    int* orow = out + (size_t)bm * PP;
    for (int j = 0; j < PER_T; ++j) {
        const int p = j * NT + t;
        orow[p] = selected(keys[p], (unsigned)p, vs, ps) ? 1 : 0;
    }
}

extern "C" void kernel_launch(void* const* d_in, const int* in_sizes, int n_in,
                              void* d_out, int out_size, void* d_ws, size_t ws_size,
                              hipStream_t stream)
{
    (void)in_sizes; (void)n_in; (void)out_size;
    const float* centers      = (const float*)d_in[0];
    const float* rand_centers = (const float*)d_in[1];
    const float* rand_mask    = (const float*)d_in[2];
    int* out = (int*)d_out;

    hipFuncSetAttribute((const void*)bpm_centers,
                        hipFuncAttributeMaxDynamicSharedMemorySize, SHM_BYTES);
    hipFuncSetAttribute((const void*)bpm_knn,
                        hipFuncAttributeMaxDynamicSharedMemorySize, SHM_BYTES);
    hipFuncSetAttribute((const void*)bpm_final,
                        hipFuncAttributeMaxDynamicSharedMemorySize, SHM_BYTES);
    hipFuncSetAttribute((const void*)bpm_mono,
                        hipFuncAttributeMaxDynamicSharedMemorySize, SHM_BYTES);

    if (ws_size >= WS_NEED_BYTES) {
        unsigned* ws_cl = (unsigned*)d_ws;
        unsigned* uni   = ws_cl + WS_CL_U32;
        bpm_centers<<<dim3(NROW), dim3(NT), SHM_BYTES, stream>>>(rand_centers, ws_cl, uni);
        bpm_knn<<<dim3(NC, NROW), dim3(NT), SHM_BYTES, stream>>>(centers, ws_cl, uni);
        bpm_final<<<dim3(NROW), dim3(NT), SHM_BYTES, stream>>>(rand_mask, uni, out);
    } else {
        bpm_mono<<<dim3(NROW), dim3(NT), SHM_BYTES, stream>>>(centers, rand_centers,
                                                              rand_mask, out);
    }
}

// Round 7
// 208.718 us; speedup vs baseline: 2.4086x; 1.0364x over previous
//
#include <hip/hip_runtime.h>

// BlockPatchMasking — exact reproduction, round 6 (resubmitted after
// GPUAcquisitionTimeout; no bench data was produced for this source).
// B=64,P=16384,F=3,MM=2 -> 128 rows. centers=10, knn=819, num_masks=9830.
// Bit-exact verified rounds 3-5 (absmax 0). d2 scheme (verified exact):
//   s2/q2 = ((x*x+y*y)+z*z) plain RN; dot = fma chain; d2 = RN(RN(s2+q2)-RN(2*dot))
//
// Round-6 structure (why): r5 showed latency-bound select (16 waves/CU, no
// gain from removing scans) + CAP overflow fallback for uniform keys.
// Now: 12-bit pass0 (4096 bins -> crossing bin ~250-1100), keys stored as
// TOP-16 bits only (u16, 32KB) -> light scans; full keys recomputed via one
// noinline fn (bit-identical everywhere); LDS 53KB -> 3 blocks/CU (24 waves).

#define PP     16384
#define NROW   128
#define NC     10
#define KNN    819
#define NMASK  9830
#define NT     512
#define PER_T  (PP / NT)   // 32
#define CAP2   2048
#define CPT2   (CAP2 / NT) // 4

#define UNI_WORDS_PER_ROW (PP / 32)
#define WS_CL_U32   (NROW * 16)
#define WS_UNI_U32  (NROW * UNI_WORDS_PER_ROW)   // 65536 == NROW*NT
#define WS_NEED_BYTES ((size_t)(WS_CL_U32 + WS_UNI_U32) * 4)

__device__ __forceinline__ unsigned mapf(float f) {
    unsigned u = __float_as_uint(f);
    return (u & 0x80000000u) ? ~u : (u | 0x80000000u);
}

// Canonical d2 — noinline so every call site (keygen, narrowing, marking)
// executes the SAME machine code -> bit-identical recomputation.
__attribute__((noinline)) __device__ float
d2_full(const float* __restrict__ crow, int p, float sx, float sy, float sz, float s2)
{
    const float cx = crow[3 * p + 0], cy = crow[3 * p + 1], cz = crow[3 * p + 2];
    const float q2 = __fadd_rn(__fadd_rn(__fmul_rn(cx, cx), __fmul_rn(cy, cy)),
                               __fmul_rn(cz, cz));
    float dot = __fmul_rn(sx, cx);
    dot = __fmaf_rn(sy, cy, dot);
    dot = __fmaf_rn(sz, cz, dot);
    return __fsub_rn(__fadd_rn(s2, q2), __fmul_rn(2.0f, dot));
}

// ---- pick helpers: find bin whose cumulative count crosses kk ----
// nbins <= 512, one bin per thread (threads t<nbins; full-wave-safe shfl use)
__device__ void hist_pick(unsigned* hist, volatile unsigned* sh, int nbins,
                          int* kk_io, unsigned* bin_out)
{
    const int t = threadIdx.x, lane = t & 63, wv = t >> 6;
    const int kk = *kk_io;
    int c = 0, x = 0;
    if (t < nbins) {
        c = (int)hist[t]; x = c;
        #pragma unroll
        for (int off = 1; off < 64; off <<= 1) {
            const int y = __shfl_up(x, off, 64);
            if (lane >= off) x += y;
        }
        if (lane == 63) sh[4 + wv] = (unsigned)x;
    }
    __syncthreads();
    if (t < nbins) {
        int base = 0;
        for (int w = 0; w < wv; ++w) base += (int)sh[4 + w];
        x += base;
        const int e = x - c;
        if (e < kk && kk <= x) { sh[0] = (unsigned)t; sh[1] = (unsigned)(kk - e); }
    }
    __syncthreads();
    *bin_out = sh[0];
    *kk_io = (int)sh[1];
    __syncthreads();
}

// 4096 bins, 8 contiguous bins per thread
__device__ void pick4096(unsigned* hist, volatile unsigned* sh, int* kk_io,
                         unsigned* bin_out)
{
    const int t = threadIdx.x, lane = t & 63, wv = t >> 6;
    const int kk = *kk_io;
    unsigned c[8]; int s = 0;
    #pragma unroll
    for (int i = 0; i < 8; ++i) { c[i] = hist[t * 8 + i]; s += (int)c[i]; }
    int x = s;
    #pragma unroll
    for (int off = 1; off < 64; off <<= 1) {
        const int y = __shfl_up(x, off, 64);
        if (lane >= off) x += y;
    }
    if (lane == 63) sh[4 + wv] = (unsigned)x;
    __syncthreads();
    int base = 0;
    for (int w = 0; w < wv; ++w) base += (int)sh[4 + w];
    x += base;
    const int e = x - s;
    if (e < kk && kk <= x) {
        int cum = e; unsigned bin = 0, rank = 0; bool found = false;
        #pragma unroll
        for (int i = 0; i < 8; ++i) {
            if (!found && kk <= cum + (int)c[i]) { bin = (unsigned)(t * 8 + i); rank = (unsigned)(kk - cum); found = true; }
            cum += (int)c[i];
        }
        sh[0] = bin; sh[1] = rank;
    }
    __syncthreads();
    *bin_out = sh[0];
    *kk_io = (int)sh[1];
    __syncthreads();
}

struct Lvl { int shift; int bins; };

// Narrow candidate list (C <= CAP2, all sharing vpref's resolved top bits).
template <class FK>
__device__ void narrow_cand(const FK& fullkey, unsigned short* cand, unsigned* ccnt,
                            unsigned* hist, volatile unsigned* sh,
                            unsigned C, int kk, unsigned vpref,
                            const Lvl* lv, int nlv,
                            unsigned& vstar, unsigned& pstar)
{
    const int t = threadIdx.x;
    for (int li = 0; li < nlv && C > 64u; ++li) {
        const int shift = lv[li].shift, bins = lv[li].bins;
        const unsigned mask = (unsigned)(bins - 1);
        if (t < bins) hist[t] = 0;
        __syncthreads();
        unsigned ci[CPT2], bb[CPT2]; bool va[CPT2];
        #pragma unroll
        for (int i = 0; i < CPT2; ++i) {
            const unsigned pos = (unsigned)(i * NT + t);
            va[i] = pos < C;
            ci[i] = va[i] ? (unsigned)cand[pos] : 0u;
            bb[i] = 0u;
            if (va[i]) { bb[i] = (fullkey(ci[i]) >> shift) & mask; atomicAdd(&hist[bb[i]], 1u); }
        }
        __syncthreads();
        unsigned bl; hist_pick(hist, sh, bins, &kk, &bl);
        vpref |= bl << shift;
        if (t == 0) *ccnt = 0;
        __syncthreads();
        #pragma unroll
        for (int i = 0; i < CPT2; ++i)
            if (va[i] && bb[i] == bl) cand[atomicAdd(ccnt, 1u)] = (unsigned short)ci[i];
        __syncthreads();
        C = *ccnt;
        __syncthreads();
    }
    if (C <= 64u) {
        if (t < 64) {
            unsigned v = 0xFFFFFFFFu, pidx = 0xFFFFu;
            if ((unsigned)t < C) { pidx = (unsigned)cand[t]; v = fullkey(pidx); }
            int rank = 0;
            for (unsigned j = 0; j < C; ++j) {
                const unsigned vj = __shfl(v, (int)j, 64);
                const unsigned pj = __shfl(pidx, (int)j, 64);
                if (vj < v || (vj == v && pj < pidx)) ++rank;
            }
            if ((unsigned)t < C && rank == kk - 1) { sh[0] = v; sh[1] = pidx; }
        }
        __syncthreads();
        vstar = sh[0]; pstar = sh[1];
        __syncthreads();
        return;
    }
    // all candidates share the full value vpref; select kk-th index
    vstar = vpref;
    if (t < 128) hist[t] = 0;
    __syncthreads();
    {
        unsigned ci[CPT2], bb[CPT2]; bool va[CPT2];
        #pragma unroll
        for (int i = 0; i < CPT2; ++i) {
            const unsigned pos = (unsigned)(i * NT + t);
            va[i] = pos < C;
            ci[i] = va[i] ? (unsigned)cand[pos] : 0u;
            bb[i] = ci[i] >> 7;
            if (va[i]) atomicAdd(&hist[bb[i]], 1u);
        }
        __syncthreads();
        unsigned bl; hist_pick(hist, sh, 128, &kk, &bl);
        if (t == 0) *ccnt = 0;
        __syncthreads();
        #pragma unroll
        for (int i = 0; i < CPT2; ++i)
            if (va[i] && bb[i] == bl) cand[atomicAdd(ccnt, 1u)] = (unsigned short)ci[i];
        __syncthreads();
        C = *ccnt;      // <= 128
        __syncthreads();
    }
    if (t < 64) {
        unsigned p0 = 0xFFFFFFFFu, p1 = 0xFFFFFFFFu;
        if ((unsigned)t < C)        p0 = (unsigned)cand[t];
        if ((unsigned)(t + 64) < C) p1 = (unsigned)cand[t + 64];
        int r0 = 0, r1 = 0;
        for (unsigned j = 0; j < C; ++j) {
            const unsigned pj = (j < 64) ? __shfl(p0, (int)j, 64)
                                         : __shfl(p1, (int)(j - 64), 64);
            if (pj < p0) ++r0;
            if (pj < p1) ++r1;
        }
        if ((unsigned)t < C && r0 == kk - 1)        sh[1] = p0;
        if ((unsigned)(t + 64) < C && r1 == kk - 1) sh[1] = p1;
    }
    __syncthreads();
    pstar = sh[1];
    __syncthreads();
}

// Exact, slow, practically-unreachable fallback: full radix with recompute.
template <class FK>
__device__ void fallback_radix(const FK& fullkey, unsigned* hist, volatile unsigned* sh,
                               int k, unsigned& vstar, unsigned& pstar)
{
    const int t = threadIdx.x;
    int kk = k; unsigned prefix = 0;
    for (int pass = 0; pass < 4; ++pass) {
        const int shift = 24 - pass * 8;
        if (t < 256) hist[t] = 0;
        __syncthreads();
        for (int j = 0; j < PER_T; ++j) {
            const unsigned p = (unsigned)(j * NT + t);
            const unsigned v = fullkey(p);
            bool in = (pass == 0) || ((v >> (shift + 8)) == prefix);
            if (in) atomicAdd(&hist[(v >> shift) & 255u], 1u);
        }
        __syncthreads();
        unsigned b; hist_pick(hist, sh, 256, &kk, &b);
        prefix = (prefix << 8) | b;
    }
    vstar = prefix;
    unsigned ipref = 0;
    for (int pass = 0; pass < 2; ++pass) {
        const int shift = 7 - pass * 7;
        if (t < 128) hist[t] = 0;
        __syncthreads();
        for (int j = 0; j < PER_T; ++j) {
            const unsigned p = (unsigned)(j * NT + t);
            bool in = (fullkey(p) == vstar);
            if (in && pass != 0) in = ((p >> (shift + 7)) == ipref);
            if (in) atomicAdd(&hist[(p >> shift) & 127u], 1u);
        }
        __syncthreads();
        unsigned b; hist_pick(hist, sh, 128, &kk, &b);
        ipref = (ipref << 7) | b;
    }
    pstar = ipref;
}

// Main select: caller has filled keys16[] (top 16 bits) and hist[4096] (top-12 hist).
template <class FK>
__device__ void select16(const FK& fullkey, const unsigned short* keys16,
                         unsigned* hist, volatile unsigned* sh,
                         unsigned short* cand, unsigned* ccnt, int k,
                         unsigned& vstar, unsigned& pstar)
{
    const int t = threadIdx.x;
    int kk = k;
    unsigned b0; pick4096(hist, sh, &kk, &b0);

    if (t == 0) *ccnt = 0;
    __syncthreads();
    for (int j = 0; j < PER_T; ++j) {
        const unsigned p = (unsigned)(j * NT + t);
        if ((unsigned)(keys16[p] >> 4) == b0) {
            const unsigned pos = atomicAdd(ccnt, 1u);
            if (pos < CAP2) cand[pos] = (unsigned short)p;
        }
    }
    __syncthreads();
    unsigned C = *ccnt;
    __syncthreads();
    if (C <= CAP2) {
        const Lvl lvA[3] = { {12, 256}, {4, 256}, {0, 16} };
        narrow_cand(fullkey, cand, ccnt, hist, sh, C, kk, b0 << 20, lvA, 3, vstar, pstar);
        return;
    }
    // rare: refine by keys16 low nibble (light scan)
    if (t < 16) hist[t] = 0;
    __syncthreads();
    for (int j = 0; j < PER_T; ++j) {
        const unsigned p = (unsigned)(j * NT + t);
        const unsigned k16 = keys16[p];
        if ((k16 >> 4) == b0) atomicAdd(&hist[k16 & 15u], 1u);
    }
    __syncthreads();
    unsigned b1; hist_pick(hist, sh, 16, &kk, &b1);
    const unsigned pref16 = (b0 << 4) | b1;
    if (t == 0) *ccnt = 0;
    __syncthreads();
    for (int j = 0; j < PER_T; ++j) {
        const unsigned p = (unsigned)(j * NT + t);
        if ((unsigned)keys16[p] == pref16) {
            const unsigned pos = atomicAdd(ccnt, 1u);
            if (pos < CAP2) cand[pos] = (unsigned short)p;
        }
    }
    __syncthreads();
    C = *ccnt;
    __syncthreads();
    if (C <= CAP2) {
        const Lvl lvB[2] = { {8, 256}, {0, 256} };
        narrow_cand(fullkey, cand, ccnt, hist, sh, C, kk, pref16 << 16, lvB, 2, vstar, pstar);
        return;
    }
    fallback_radix(fullkey, hist, sh, k, vstar, pstar);
}

#define DECL_SHARED                                         \
    __shared__ unsigned short keys16[PP];                   \
    __shared__ unsigned hist[4096];                         \
    __shared__ unsigned sh_[8];                             \
    __shared__ unsigned ccnt_s;                             \
    __shared__ unsigned short cand[CAP2];                   \
    volatile unsigned* sh = (volatile unsigned*)sh_;

// ---- kernel A: 10 smallest rand_centers per row -> ws clist; clears uni ----
extern "C" __global__ void __launch_bounds__(NT, 6)
bpm_centers(const float* __restrict__ rand_centers, unsigned* __restrict__ ws_cl,
            unsigned* __restrict__ uni)
{
    DECL_SHARED
    __shared__ unsigned clist[16];
    __shared__ unsigned pcnt;

    const int bm = blockIdx.x;
    const int t  = threadIdx.x;
    uni[bm * NT + t] = 0u;                       // clear union bitmap

    const float* rcrow = rand_centers + (size_t)bm * PP;
    auto fullkey = [rcrow](unsigned p) -> unsigned { return mapf(rcrow[p]); };

    #pragma unroll
    for (int i = 0; i < 8; ++i) hist[t * 8 + i] = 0;
    if (t == 0) pcnt = 0;
    __syncthreads();
    for (int j = 0; j < PER_T; ++j) {
        const int p = j * NT + t;
        const unsigned k32 = fullkey((unsigned)p);
        keys16[p] = (unsigned short)(k32 >> 16);
        atomicAdd(&hist[k32 >> 20], 1u);
    }
    __syncthreads();

    unsigned vs, ps;
    select16(fullkey, keys16, hist, sh, cand, &ccnt_s, NC, vs, ps);
    const unsigned vs16 = vs >> 16;

    for (int j = 0; j < PER_T; ++j) {
        const unsigned p = (unsigned)(j * NT + t);
        const unsigned k16 = keys16[p];
        bool sel = false;
        if (k16 < vs16) sel = true;
        else if (k16 == vs16) {
            const unsigned v = fullkey(p);
            sel = (v < vs) || (v == vs && p <= ps);
        }
        if (sel) clist[atomicAdd(&pcnt, 1u)] = p;   // order irrelevant (set union)
    }
    __syncthreads();
    if (t < NC) ws_cl[bm * 16 + t] = clist[t];
}

// ---- kernel B: one block per (row, center): 819-NN -> atomicOr bitmap ----
extern "C" __global__ void __launch_bounds__(NT, 6)
bpm_knn(const float* __restrict__ centers, const unsigned* __restrict__ ws_cl,
        unsigned* __restrict__ uni)
{
    DECL_SHARED
    const int c  = blockIdx.x;
    const int bm = blockIdx.y;
    const int b  = bm >> 1;
    const int t  = threadIdx.x;
    const float* crow = centers + (size_t)b * PP * 3;

    const int ci = (int)ws_cl[bm * 16 + c];
    const float sx = crow[ci * 3 + 0];
    const float sy = crow[ci * 3 + 1];
    const float sz = crow[ci * 3 + 2];
    const float s2 = __fadd_rn(__fadd_rn(__fmul_rn(sx, sx), __fmul_rn(sy, sy)),
                               __fmul_rn(sz, sz));
    auto fullkey = [crow, sx, sy, sz, s2](unsigned p) -> unsigned {
        return mapf(d2_full(crow, (int)p, sx, sy, sz, s2));
    };

    #pragma unroll
    for (int i = 0; i < 8; ++i) hist[t * 8 + i] = 0;
    __syncthreads();
    for (int j = 0; j < PER_T; ++j) {
        const int p = j * NT + t;
        const unsigned k32 = fullkey((unsigned)p);
        keys16[p] = (unsigned short)(k32 >> 16);
        atomicAdd(&hist[k32 >> 20], 1u);
    }
    __syncthreads();

    unsigned vs, ps;
    select16(fullkey, keys16, hist, sh, cand, &ccnt_s, KNN, vs, ps);
    const unsigned vs16 = vs >> 16;

    unsigned* urow = uni + (size_t)bm * UNI_WORDS_PER_ROW;
    for (int j = 0; j < PER_T; ++j) {
        const unsigned p = (unsigned)(j * NT + t);
        const unsigned k16 = keys16[p];
        bool sel = false;
        if (k16 < vs16) sel = true;
        else if (k16 == vs16) {
            const unsigned v = fullkey(p);
            sel = (v < vs) || (v == vs && p <= ps);
        }
        const unsigned long long bmask = __ballot(sel);
        if ((t & 63) == 0 && bmask) {
            const int wbase = (int)(p >> 5);
            const unsigned lo = (unsigned)bmask;
            const unsigned hi = (unsigned)(bmask >> 32);
            if (lo) atomicOr(&urow[wbase], lo);
            if (hi) atomicOr(&urow[wbase + 1], hi);
        }
    }
}

// ---- kernel C: flip by union bit, select 9830, write int mask ----
extern "C" __global__ void __launch_bounds__(NT, 6)
bpm_final(const float* __restrict__ rand_mask, const unsigned* __restrict__ uni,
          int* __restrict__ out)
{
    DECL_SHARED
    const int bm = blockIdx.x;
    const int t  = threadIdx.x;
    const float* rmrow = rand_mask + (size_t)bm * PP;
    const unsigned* urow = uni + (size_t)bm * UNI_WORDS_PER_ROW;

    auto fullkey = [rmrow, urow](unsigned p) -> unsigned {
        const float r = rmrow[p];
        const bool inb = (urow[p >> 5] >> (p & 31)) & 1u;
        return mapf(inb ? -r : r);
    };

    #pragma unroll
    for (int i = 0; i < 8; ++i) hist[t * 8 + i] = 0;
    __syncthreads();
    for (int j = 0; j < PER_T; ++j) {
        const int p = j * NT + t;
        const unsigned k32 = fullkey((unsigned)p);
        keys16[p] = (unsigned short)(k32 >> 16);
        atomicAdd(&hist[k32 >> 20], 1u);
    }
    __syncthreads();

    unsigned vs, ps;
    select16(fullkey, keys16, hist, sh, cand, &ccnt_s, NMASK, vs, ps);
    const unsigned vs16 = vs >> 16;

    int* orow = out + (size_t)bm * PP;
    for (int j = 0; j < PER_T; ++j) {
        const unsigned p = (unsigned)(j * NT + t);
        const unsigned k16 = keys16[p];
        bool sel = false;
        if (k16 < vs16) sel = true;
        else if (k16 == vs16) {
            const unsigned v = fullkey(p);
            sel = (v < vs) || (v == vs && p <= ps);
        }
        orow[p] = sel ? 1 : 0;
    }
}

extern "C" void kernel_launch(void* const* d_in, const int* in_sizes, int n_in,
                              void* d_out, int out_size, void* d_ws, size_t ws_size,
                              hipStream_t stream)
{
    (void)in_sizes; (void)n_in; (void)out_size; (void)ws_size;
    const float* centers      = (const float*)d_in[0];
    const float* rand_centers = (const float*)d_in[1];
    const float* rand_mask    = (const float*)d_in[2];
    int* out = (int*)d_out;

    unsigned* ws_cl = (unsigned*)d_ws;          // ws_size >= 264KB verified r4/r5
    unsigned* uni   = ws_cl + WS_CL_U32;

    bpm_centers<<<dim3(NROW), dim3(NT), 0, stream>>>(rand_centers, ws_cl, uni);
    bpm_knn<<<dim3(NC, NROW), dim3(NT), 0, stream>>>(centers, ws_cl, uni);
    bpm_final<<<dim3(NROW), dim3(NT), 0, stream>>>(rand_mask, uni, out);
}

// Round 8
// 179.309 us; speedup vs baseline: 2.8037x; 1.1640x over previous
//
#include <hip/hip_runtime.h>

// BlockPatchMasking — exact reproduction, round 8.
// B=64,P=16384,F=3,MM=2 -> 128 rows. centers=10, knn=819, num_masks=9830.
// Bit-exact verified rounds 3-7 (absmax 0).
// d2 scheme (verified exact): s2/q2 = ((x*x+y*y)+z*z) plain RN;
//   dot = fma chain; d2 = RN(RN(s2+q2) - RN(2*dot)).
//
// r7 post-mortem: knn latency-bound (VALU 27%) — r6's noinline d2_full with
// loads INSIDE serialized keygen (no MLP). This round: d2_core = forceinline
// pure arithmetic (explicit _rn intrinsics -> bit-identical at every inline
// site), loads in callers, unroll-4 scans, 1024-bin narrow levels (2 max,
// typically 1) instead of 3x256.

#define PP     16384
#define NROW   128
#define NC     10
#define KNN    819
#define NMASK  9830
#define NT     512
#define PER_T  (PP / NT)   // 32
#define CAP2   2048
#define CPT2   (CAP2 / NT) // 4

#define UNI_WORDS_PER_ROW (PP / 32)
#define WS_CL_U32   (NROW * 16)

__device__ __forceinline__ unsigned mapf(float f) {
    unsigned u = __float_as_uint(f);
    return (u & 0x80000000u) ? ~u : (u | 0x80000000u);
}

// Canonical d2 arithmetic. Explicit RN intrinsics are non-fusable and
// non-reassociable -> every inlined copy computes bit-identical results.
__device__ __forceinline__ float
d2_core(float cx, float cy, float cz, float sx, float sy, float sz, float s2)
{
    const float q2 = __fadd_rn(__fadd_rn(__fmul_rn(cx, cx), __fmul_rn(cy, cy)),
                               __fmul_rn(cz, cz));
    float dot = __fmul_rn(sx, cx);
    dot = __fmaf_rn(sy, cy, dot);
    dot = __fmaf_rn(sz, cz, dot);
    return __fsub_rn(__fadd_rn(s2, q2), __fmul_rn(2.0f, dot));
}

// ---- pick: find bin whose cumulative count crosses kk ----
// hist_pick: nbins <= 512, one bin per thread (t < nbins).
__device__ void hist_pick(unsigned* hist, volatile unsigned* sh, int nbins,
                          int* kk_io, unsigned* bin_out)
{
    const int t = threadIdx.x, lane = t & 63, wv = t >> 6;
    const int kk = *kk_io;
    int c = 0, x = 0;
    if (t < nbins) {
        c = (int)hist[t]; x = c;
        #pragma unroll
        for (int off = 1; off < 64; off <<= 1) {
            const int y = __shfl_up(x, off, 64);
            if (lane >= off) x += y;
        }
        if (lane == 63) sh[4 + wv] = (unsigned)x;
    }
    __syncthreads();
    if (t < nbins) {
        int base = 0;
        for (int w = 0; w < wv; ++w) base += (int)sh[4 + w];
        x += base;
        const int e = x - c;
        if (e < kk && kk <= x) { sh[0] = (unsigned)t; sh[1] = (unsigned)(kk - e); }
    }
    __syncthreads();
    *bin_out = sh[0];
    *kk_io = (int)sh[1];
    __syncthreads();
}

// pick_bpt<BPT>: NT*BPT bins, BPT contiguous bins per thread (static indexing).
template <int BPT>
__device__ void pick_bpt(unsigned* hist, volatile unsigned* sh,
                         int* kk_io, unsigned* bin_out)
{
    const int t = threadIdx.x, lane = t & 63, wv = t >> 6;
    const int kk = *kk_io;
    unsigned c[BPT]; int s = 0;
    #pragma unroll
    for (int i = 0; i < BPT; ++i) { c[i] = hist[t * BPT + i]; s += (int)c[i]; }
    int x = s;
    #pragma unroll
    for (int off = 1; off < 64; off <<= 1) {
        const int y = __shfl_up(x, off, 64);
        if (lane >= off) x += y;
    }
    if (lane == 63) sh[4 + wv] = (unsigned)x;
    __syncthreads();
    int base = 0;
    for (int w = 0; w < wv; ++w) base += (int)sh[4 + w];
    x += base;
    const int e = x - s;
    if (e < kk && kk <= x) {
        int cum = e; unsigned bin = 0, rank = 0; bool found = false;
        #pragma unroll
        for (int i = 0; i < BPT; ++i) {
            if (!found && kk <= cum + (int)c[i]) {
                bin = (unsigned)(t * BPT + i); rank = (unsigned)(kk - cum); found = true;
            }
            cum += (int)c[i];
        }
        sh[0] = bin; sh[1] = rank;
    }
    __syncthreads();
    *bin_out = sh[0];
    *kk_io = (int)sh[1];
    __syncthreads();
}

struct Lvl { int shift; int bins; };

// Narrow candidate list (C <= CAP2, all sharing vpref's resolved top bits).
template <class FK>
__device__ void narrow_cand(const FK& fullkey, unsigned short* cand, unsigned* ccnt,
                            unsigned* hist, volatile unsigned* sh,
                            unsigned C, int kk, unsigned vpref,
                            const Lvl* lv, int nlv,
                            unsigned& vstar, unsigned& pstar)
{
    const int t = threadIdx.x;
    for (int li = 0; li < nlv && C > 64u; ++li) {
        const int shift = lv[li].shift, bins = lv[li].bins;
        const unsigned mask = (unsigned)(bins - 1);
        for (int i = t; i < bins; i += NT) hist[i] = 0;
        __syncthreads();
        unsigned ci[CPT2], bb[CPT2]; bool va[CPT2];
        #pragma unroll
        for (int i = 0; i < CPT2; ++i) {
            const unsigned pos = (unsigned)(i * NT + t);
            va[i] = pos < C;
            ci[i] = va[i] ? (unsigned)cand[pos] : 0u;
            bb[i] = 0u;
            if (va[i]) { bb[i] = (fullkey(ci[i]) >> shift) & mask; atomicAdd(&hist[bb[i]], 1u); }
        }
        __syncthreads();
        unsigned bl;
        if (bins == 1024) pick_bpt<2>(hist, sh, &kk, &bl);
        else              hist_pick(hist, sh, bins, &kk, &bl);
        vpref |= bl << shift;
        if (t == 0) *ccnt = 0;
        __syncthreads();
        #pragma unroll
        for (int i = 0; i < CPT2; ++i)
            if (va[i] && bb[i] == bl) cand[atomicAdd(ccnt, 1u)] = (unsigned short)ci[i];
        __syncthreads();
        C = *ccnt;
        __syncthreads();
    }
    if (C <= 64u) {
        if (t < 64) {
            unsigned v = 0xFFFFFFFFu, pidx = 0xFFFFu;
            if ((unsigned)t < C) { pidx = (unsigned)cand[t]; v = fullkey(pidx); }
            int rank = 0;
            for (unsigned j = 0; j < C; ++j) {
                const unsigned vj = __shfl(v, (int)j, 64);
                const unsigned pj = __shfl(pidx, (int)j, 64);
                if (vj < v || (vj == v && pj < pidx)) ++rank;
            }
            if ((unsigned)t < C && rank == kk - 1) { sh[0] = v; sh[1] = pidx; }
        }
        __syncthreads();
        vstar = sh[0]; pstar = sh[1];
        __syncthreads();
        return;
    }
    // all candidates share the full value vpref; select kk-th index
    vstar = vpref;
    if (t < 128) hist[t] = 0;
    __syncthreads();
    {
        unsigned ci[CPT2], bb[CPT2]; bool va[CPT2];
        #pragma unroll
        for (int i = 0; i < CPT2; ++i) {
            const unsigned pos = (unsigned)(i * NT + t);
            va[i] = pos < C;
            ci[i] = va[i] ? (unsigned)cand[pos] : 0u;
            bb[i] = ci[i] >> 7;
            if (va[i]) atomicAdd(&hist[bb[i]], 1u);
        }
        __syncthreads();
        unsigned bl; hist_pick(hist, sh, 128, &kk, &bl);
        if (t == 0) *ccnt = 0;
        __syncthreads();
        #pragma unroll
        for (int i = 0; i < CPT2; ++i)
            if (va[i] && bb[i] == bl) cand[atomicAdd(ccnt, 1u)] = (unsigned short)ci[i];
        __syncthreads();
        C = *ccnt;      // <= 128
        __syncthreads();
    }
    if (t < 64) {
        unsigned p0 = 0xFFFFFFFFu, p1 = 0xFFFFFFFFu;
        if ((unsigned)t < C)        p0 = (unsigned)cand[t];
        if ((unsigned)(t + 64) < C) p1 = (unsigned)cand[t + 64];
        int r0 = 0, r1 = 0;
        for (unsigned j = 0; j < C; ++j) {
            const unsigned pj = (j < 64) ? __shfl(p0, (int)j, 64)
                                         : __shfl(p1, (int)(j - 64), 64);
            if (pj < p0) ++r0;
            if (pj < p1) ++r1;
        }
        if ((unsigned)t < C && r0 == kk - 1)        sh[1] = p0;
        if ((unsigned)(t + 64) < C && r1 == kk - 1) sh[1] = p1;
    }
    __syncthreads();
    pstar = sh[1];
    __syncthreads();
}

// Exact, slow, practically-unreachable fallback: full radix with recompute.
template <class FK>
__device__ void fallback_radix(const FK& fullkey, unsigned* hist, volatile unsigned* sh,
                               int k, unsigned& vstar, unsigned& pstar)
{
    const int t = threadIdx.x;
    int kk = k; unsigned prefix = 0;
    for (int pass = 0; pass < 4; ++pass) {
        const int shift = 24 - pass * 8;
        if (t < 256) hist[t] = 0;
        __syncthreads();
        for (int j = 0; j < PER_T; ++j) {
            const unsigned p = (unsigned)(j * NT + t);
            const unsigned v = fullkey(p);
            bool in = (pass == 0) || ((v >> (shift + 8)) == prefix);
            if (in) atomicAdd(&hist[(v >> shift) & 255u], 1u);
        }
        __syncthreads();
        unsigned b; hist_pick(hist, sh, 256, &kk, &b);
        prefix = (prefix << 8) | b;
    }
    vstar = prefix;
    unsigned ipref = 0;
    for (int pass = 0; pass < 2; ++pass) {
        const int shift = 7 - pass * 7;
        if (t < 128) hist[t] = 0;
        __syncthreads();
        for (int j = 0; j < PER_T; ++j) {
            const unsigned p = (unsigned)(j * NT + t);
            bool in = (fullkey(p) == vstar);
            if (in && pass != 0) in = ((p >> (shift + 7)) == ipref);
            if (in) atomicAdd(&hist[(p >> shift) & 127u], 1u);
        }
        __syncthreads();
        unsigned b; hist_pick(hist, sh, 128, &kk, &b);
        ipref = (ipref << 7) | b;
    }
    pstar = ipref;
}

// Main select: caller filled keys16[] (top 16 bits) and hist[4096] (top-12 hist).
template <class FK>
__device__ void select16(const FK& fullkey, const unsigned short* keys16,
                         unsigned* hist, volatile unsigned* sh,
                         unsigned short* cand, unsigned* ccnt, int k,
                         unsigned& vstar, unsigned& pstar)
{
    const int t = threadIdx.x;
    int kk = k;
    unsigned b0; pick_bpt<8>(hist, sh, &kk, &b0);

    if (t == 0) *ccnt = 0;
    __syncthreads();
    #pragma unroll 4
    for (int j = 0; j < PER_T; ++j) {
        const unsigned p = (unsigned)(j * NT + t);
        if ((unsigned)(keys16[p] >> 4) == b0) {
            const unsigned pos = atomicAdd(ccnt, 1u);
            if (pos < CAP2) cand[pos] = (unsigned short)p;
        }
    }
    __syncthreads();
    unsigned C = *ccnt;
    __syncthreads();
    if (C <= CAP2) {
        const Lvl lvA[2] = { {10, 1024}, {0, 1024} };
        narrow_cand(fullkey, cand, ccnt, hist, sh, C, kk, b0 << 20, lvA, 2, vstar, pstar);
        return;
    }
    // rare: refine by keys16 low nibble (light scan)
    if (t < 16) hist[t] = 0;
    __syncthreads();
    #pragma unroll 4
    for (int j = 0; j < PER_T; ++j) {
        const unsigned p = (unsigned)(j * NT + t);
        const unsigned k16 = keys16[p];
        if ((k16 >> 4) == b0) atomicAdd(&hist[k16 & 15u], 1u);
    }
    __syncthreads();
    unsigned b1; hist_pick(hist, sh, 16, &kk, &b1);
    const unsigned pref16 = (b0 << 4) | b1;
    if (t == 0) *ccnt = 0;
    __syncthreads();
    #pragma unroll 4
    for (int j = 0; j < PER_T; ++j) {
        const unsigned p = (unsigned)(j * NT + t);
        if ((unsigned)keys16[p] == pref16) {
            const unsigned pos = atomicAdd(ccnt, 1u);
            if (pos < CAP2) cand[pos] = (unsigned short)p;
        }
    }
    __syncthreads();
    C = *ccnt;
    __syncthreads();
    if (C <= CAP2) {
        const Lvl lvB[2] = { {8, 256}, {0, 256} };
        narrow_cand(fullkey, cand, ccnt, hist, sh, C, kk, pref16 << 16, lvB, 2, vstar, pstar);
        return;
    }
    fallback_radix(fullkey, hist, sh, k, vstar, pstar);
}

#define DECL_SHARED                                         \
    __shared__ unsigned short keys16[PP];                   \
    __shared__ unsigned hist[4096];                         \
    __shared__ unsigned sh_[8];                             \
    __shared__ unsigned ccnt_s;                             \
    __shared__ unsigned short cand[CAP2];                   \
    volatile unsigned* sh = (volatile unsigned*)sh_;

// ---- kernel A: 10 smallest rand_centers per row -> ws clist; clears uni ----
extern "C" __global__ void __launch_bounds__(NT, 6)
bpm_centers(const float* __restrict__ rand_centers, unsigned* __restrict__ ws_cl,
            unsigned* __restrict__ uni)
{
    DECL_SHARED
    __shared__ unsigned clist[16];
    __shared__ unsigned pcnt;

    const int bm = blockIdx.x;
    const int t  = threadIdx.x;
    uni[bm * NT + t] = 0u;                       // clear union bitmap

    const float* rcrow = rand_centers + (size_t)bm * PP;
    auto fullkey = [rcrow](unsigned p) -> unsigned { return mapf(rcrow[p]); };

    #pragma unroll
    for (int i = 0; i < 8; ++i) hist[t * 8 + i] = 0;
    if (t == 0) pcnt = 0;
    __syncthreads();
    #pragma unroll 4
    for (int j = 0; j < PER_T; ++j) {
        const int p = j * NT + t;
        const unsigned k32 = fullkey((unsigned)p);
        keys16[p] = (unsigned short)(k32 >> 16);
        atomicAdd(&hist[k32 >> 20], 1u);
    }
    __syncthreads();

    unsigned vs, ps;
    select16(fullkey, keys16, hist, sh, cand, &ccnt_s, NC, vs, ps);
    const unsigned vs16 = vs >> 16;

    #pragma unroll 4
    for (int j = 0; j < PER_T; ++j) {
        const unsigned p = (unsigned)(j * NT + t);
        const unsigned k16 = keys16[p];
        bool sel = false;
        if (k16 < vs16) sel = true;
        else if (k16 == vs16) {
            const unsigned v = fullkey(p);
            sel = (v < vs) || (v == vs && p <= ps);
        }
        if (sel) clist[atomicAdd(&pcnt, 1u)] = p;   // order irrelevant (set union)
    }
    __syncthreads();
    if (t < NC) ws_cl[bm * 16 + t] = clist[t];
}

// ---- kernel B: one block per (row, center): 819-NN -> atomicOr bitmap ----
extern "C" __global__ void __launch_bounds__(NT, 6)
bpm_knn(const float* __restrict__ centers, const unsigned* __restrict__ ws_cl,
        unsigned* __restrict__ uni)
{
    DECL_SHARED
    const int c  = blockIdx.x;
    const int bm = blockIdx.y;
    const int b  = bm >> 1;
    const int t  = threadIdx.x;
    const float* crow = centers + (size_t)b * PP * 3;

    const int ci = (int)ws_cl[bm * 16 + c];
    const float sx = crow[ci * 3 + 0];
    const float sy = crow[ci * 3 + 1];
    const float sz = crow[ci * 3 + 2];
    const float s2 = __fadd_rn(__fadd_rn(__fmul_rn(sx, sx), __fmul_rn(sy, sy)),
                               __fmul_rn(sz, sz));
    auto fullkey = [crow, sx, sy, sz, s2](unsigned p) -> unsigned {
        const float cx = crow[3 * p + 0], cy = crow[3 * p + 1], cz = crow[3 * p + 2];
        return mapf(d2_core(cx, cy, cz, sx, sy, sz, s2));
    };

    #pragma unroll
    for (int i = 0; i < 8; ++i) hist[t * 8 + i] = 0;
    __syncthreads();
    #pragma unroll 4
    for (int j = 0; j < PER_T; ++j) {
        const int p = j * NT + t;
        const unsigned k32 = fullkey((unsigned)p);
        keys16[p] = (unsigned short)(k32 >> 16);
        atomicAdd(&hist[k32 >> 20], 1u);
    }
    __syncthreads();

    unsigned vs, ps;
    select16(fullkey, keys16, hist, sh, cand, &ccnt_s, KNN, vs, ps);
    const unsigned vs16 = vs >> 16;

    unsigned* urow = uni + (size_t)bm * UNI_WORDS_PER_ROW;
    #pragma unroll 4
    for (int j = 0; j < PER_T; ++j) {
        const unsigned p = (unsigned)(j * NT + t);
        const unsigned k16 = keys16[p];
        bool sel = false;
        if (k16 < vs16) sel = true;
        else if (k16 == vs16) {
            const unsigned v = fullkey(p);
            sel = (v < vs) || (v == vs && p <= ps);
        }
        const unsigned long long bmask = __ballot(sel);
        if ((t & 63) == 0 && bmask) {
            const int wbase = (int)(p >> 5);
            const unsigned lo = (unsigned)bmask;
            const unsigned hi = (unsigned)(bmask >> 32);
            if (lo) atomicOr(&urow[wbase], lo);
            if (hi) atomicOr(&urow[wbase + 1], hi);
        }
    }
}

// ---- kernel C: flip by union bit, select 9830, write int mask ----
extern "C" __global__ void __launch_bounds__(NT, 6)
bpm_final(const float* __restrict__ rand_mask, const unsigned* __restrict__ uni,
          int* __restrict__ out)
{
    DECL_SHARED
    const int bm = blockIdx.x;
    const int t  = threadIdx.x;
    const float* rmrow = rand_mask + (size_t)bm * PP;
    const unsigned* urow = uni + (size_t)bm * UNI_WORDS_PER_ROW;

    auto fullkey = [rmrow, urow](unsigned p) -> unsigned {
        const float r = rmrow[p];
        const bool inb = (urow[p >> 5] >> (p & 31)) & 1u;
        return mapf(inb ? -r : r);
    };

    #pragma unroll
    for (int i = 0; i < 8; ++i) hist[t * 8 + i] = 0;
    __syncthreads();
    #pragma unroll 4
    for (int j = 0; j < PER_T; ++j) {
        const int p = j * NT + t;
        const unsigned k32 = fullkey((unsigned)p);
        keys16[p] = (unsigned short)(k32 >> 16);
        atomicAdd(&hist[k32 >> 20], 1u);
    }
    __syncthreads();

    unsigned vs, ps;
    select16(fullkey, keys16, hist, sh, cand, &ccnt_s, NMASK, vs, ps);
    const unsigned vs16 = vs >> 16;

    int* orow = out + (size_t)bm * PP;
    #pragma unroll 4
    for (int j = 0; j < PER_T; ++j) {
        const unsigned p = (unsigned)(j * NT + t);
        const unsigned k16 = keys16[p];
        bool sel = false;
        if (k16 < vs16) sel = true;
        else if (k16 == vs16) {
            const unsigned v = fullkey(p);
            sel = (v < vs) || (v == vs && p <= ps);
        }
        orow[p] = sel ? 1 : 0;
    }
}

extern "C" void kernel_launch(void* const* d_in, const int* in_sizes, int n_in,
                              void* d_out, int out_size, void* d_ws, size_t ws_size,
                              hipStream_t stream)
{
    (void)in_sizes; (void)n_in; (void)out_size; (void)ws_size;
    const float* centers      = (const float*)d_in[0];
    const float* rand_centers = (const float*)d_in[1];
    const float* rand_mask    = (const float*)d_in[2];
    int* out = (int*)d_out;

    unsigned* ws_cl = (unsigned*)d_ws;          // ws_size >= 264KB verified r4-r7
    unsigned* uni   = ws_cl + WS_CL_U32;

    bpm_centers<<<dim3(NROW), dim3(NT), 0, stream>>>(rand_centers, ws_cl, uni);
    bpm_knn<<<dim3(NC, NROW), dim3(NT), 0, stream>>>(centers, ws_cl, uni);
    bpm_final<<<dim3(NROW), dim3(NT), 0, stream>>>(rand_mask, uni, out);
}

// Round 9
// 157.404 us; speedup vs baseline: 3.1938x; 1.1392x over previous
//
#include <hip/hip_runtime.h>

// BlockPatchMasking — exact reproduction, round 9.
// B=64,P=16384,F=3,MM=2 -> 128 rows. centers=10, knn=819, num_masks=9830.
// Bit-exact verified rounds 3-8 (absmax 0).
// d2 scheme (verified exact): s2/q2 = ((x*x+y*y)+z*z) plain RN;
//   dot = fma chain; d2 = RN(RN(s2+q2) - RN(2*dot)).
//
// r8 post-mortem: knn stall-bound (VALU 24%, occ 49%, FETCH 4.2x input).
// This round: NT=1024 (scans halved, 32 waves/CU), float4 keygen loads
// (coalesced 16B, same per-element arithmetic), XCD swizzle so all 10
// blocks of a row share an XCD's L2 (row 196KB -> L2-resident).

#define PP     16384
#define NROW   128
#define NC     10
#define KNN    819
#define NMASK  9830
#define NT     1024
#define PER_T  (PP / NT)       // 16
#define KG_IT  (PP / (NT * 4)) // 4 (4 points/thread/iter)
#define CAP2   2048
#define CPT2   (CAP2 / NT)     // 2

#define UNI_WPR   512          // union bitmap words per row
#define WS_CL_U32 (NROW * 16)

__device__ __forceinline__ unsigned mapf(float f) {
    unsigned u = __float_as_uint(f);
    return (u & 0x80000000u) ? ~u : (u | 0x80000000u);
}

// Canonical d2 arithmetic. Explicit RN intrinsics are non-fusable and
// non-reassociable -> every inlined copy computes bit-identical results.
__device__ __forceinline__ float
d2_core(float cx, float cy, float cz, float sx, float sy, float sz, float s2)
{
    const float q2 = __fadd_rn(__fadd_rn(__fmul_rn(cx, cx), __fmul_rn(cy, cy)),
                               __fmul_rn(cz, cz));
    float dot = __fmul_rn(sx, cx);
    dot = __fmaf_rn(sy, cy, dot);
    dot = __fmaf_rn(sz, cz, dot);
    return __fsub_rn(__fadd_rn(s2, q2), __fmul_rn(2.0f, dot));
}

// ---- pick: find bin whose cumulative count crosses kk ----
// hist_pick: nbins <= NT, one bin per thread (t < nbins).
__device__ void hist_pick(unsigned* hist, volatile unsigned* sh, int nbins,
                          int* kk_io, unsigned* bin_out)
{
    const int t = threadIdx.x, lane = t & 63, wv = t >> 6;
    const int kk = *kk_io;
    int c = 0, x = 0;
    if (t < nbins) {
        c = (int)hist[t]; x = c;
        #pragma unroll
        for (int off = 1; off < 64; off <<= 1) {
            const int y = __shfl_up(x, off, 64);
            if (lane >= off) x += y;
        }
        if (lane == 63) sh[4 + wv] = (unsigned)x;
    }
    __syncthreads();
    if (t < nbins) {
        int base = 0;
        for (int w = 0; w < wv; ++w) base += (int)sh[4 + w];
        x += base;
        const int e = x - c;
        if (e < kk && kk <= x) { sh[0] = (unsigned)t; sh[1] = (unsigned)(kk - e); }
    }
    __syncthreads();
    *bin_out = sh[0];
    *kk_io = (int)sh[1];
    __syncthreads();
}

// pick_bpt<BPT>: NT*BPT bins, BPT contiguous bins per thread (static indexing).
template <int BPT>
__device__ void pick_bpt(unsigned* hist, volatile unsigned* sh,
                         int* kk_io, unsigned* bin_out)
{
    const int t = threadIdx.x, lane = t & 63, wv = t >> 6;
    const int kk = *kk_io;
    unsigned c[BPT]; int s = 0;
    #pragma unroll
    for (int i = 0; i < BPT; ++i) { c[i] = hist[t * BPT + i]; s += (int)c[i]; }
    int x = s;
    #pragma unroll
    for (int off = 1; off < 64; off <<= 1) {
        const int y = __shfl_up(x, off, 64);
        if (lane >= off) x += y;
    }
    if (lane == 63) sh[4 + wv] = (unsigned)x;
    __syncthreads();
    int base = 0;
    for (int w = 0; w < wv; ++w) base += (int)sh[4 + w];
    x += base;
    const int e = x - s;
    if (e < kk && kk <= x) {
        int cum = e; unsigned bin = 0, rank = 0; bool found = false;
        #pragma unroll
        for (int i = 0; i < BPT; ++i) {
            if (!found && kk <= cum + (int)c[i]) {
                bin = (unsigned)(t * BPT + i); rank = (unsigned)(kk - cum); found = true;
            }
            cum += (int)c[i];
        }
        sh[0] = bin; sh[1] = rank;
    }
    __syncthreads();
    *bin_out = sh[0];
    *kk_io = (int)sh[1];
    __syncthreads();
}

struct Lvl { int shift; int bins; };

// Narrow candidate list (C <= CAP2, all sharing vpref's resolved top bits).
template <class FK>
__device__ void narrow_cand(const FK& fullkey, unsigned short* cand, unsigned* ccnt,
                            unsigned* hist, volatile unsigned* sh,
                            unsigned C, int kk, unsigned vpref,
                            const Lvl* lv, int nlv,
                            unsigned& vstar, unsigned& pstar)
{
    const int t = threadIdx.x;
    for (int li = 0; li < nlv && C > 64u; ++li) {
        const int shift = lv[li].shift, bins = lv[li].bins;
        const unsigned mask = (unsigned)(bins - 1);
        if (t < bins) hist[t] = 0;
        __syncthreads();
        unsigned ci[CPT2], bb[CPT2]; bool va[CPT2];
        #pragma unroll
        for (int i = 0; i < CPT2; ++i) {
            const unsigned pos = (unsigned)(i * NT + t);
            va[i] = pos < C;
            ci[i] = va[i] ? (unsigned)cand[pos] : 0u;
            bb[i] = 0u;
            if (va[i]) { bb[i] = (fullkey(ci[i]) >> shift) & mask; atomicAdd(&hist[bb[i]], 1u); }
        }
        __syncthreads();
        unsigned bl;
        hist_pick(hist, sh, bins, &kk, &bl);
        vpref |= bl << shift;
        if (t == 0) *ccnt = 0;
        __syncthreads();
        #pragma unroll
        for (int i = 0; i < CPT2; ++i)
            if (va[i] && bb[i] == bl) cand[atomicAdd(ccnt, 1u)] = (unsigned short)ci[i];
        __syncthreads();
        C = *ccnt;
        __syncthreads();
    }
    if (C <= 64u) {
        if (t < 64) {
            unsigned v = 0xFFFFFFFFu, pidx = 0xFFFFu;
            if ((unsigned)t < C) { pidx = (unsigned)cand[t]; v = fullkey(pidx); }
            int rank = 0;
            for (unsigned j = 0; j < C; ++j) {
                const unsigned vj = __shfl(v, (int)j, 64);
                const unsigned pj = __shfl(pidx, (int)j, 64);
                if (vj < v || (vj == v && pj < pidx)) ++rank;
            }
            if ((unsigned)t < C && rank == kk - 1) { sh[0] = v; sh[1] = pidx; }
        }
        __syncthreads();
        vstar = sh[0]; pstar = sh[1];
        __syncthreads();
        return;
    }
    // all candidates share the full value vpref; select kk-th index
    vstar = vpref;
    if (t < 128) hist[t] = 0;
    __syncthreads();
    {
        unsigned ci[CPT2], bb[CPT2]; bool va[CPT2];
        #pragma unroll
        for (int i = 0; i < CPT2; ++i) {
            const unsigned pos = (unsigned)(i * NT + t);
            va[i] = pos < C;
            ci[i] = va[i] ? (unsigned)cand[pos] : 0u;
            bb[i] = ci[i] >> 7;
            if (va[i]) atomicAdd(&hist[bb[i]], 1u);
        }
        __syncthreads();
        unsigned bl; hist_pick(hist, sh, 128, &kk, &bl);
        if (t == 0) *ccnt = 0;
        __syncthreads();
        #pragma unroll
        for (int i = 0; i < CPT2; ++i)
            if (va[i] && bb[i] == bl) cand[atomicAdd(ccnt, 1u)] = (unsigned short)ci[i];
        __syncthreads();
        C = *ccnt;      // <= 128
        __syncthreads();
    }
    if (t < 64) {
        unsigned p0 = 0xFFFFFFFFu, p1 = 0xFFFFFFFFu;
        if ((unsigned)t < C)        p0 = (unsigned)cand[t];
        if ((unsigned)(t + 64) < C) p1 = (unsigned)cand[t + 64];
        int r0 = 0, r1 = 0;
        for (unsigned j = 0; j < C; ++j) {
            const unsigned pj = (j < 64) ? __shfl(p0, (int)j, 64)
                                         : __shfl(p1, (int)(j - 64), 64);
            if (pj < p0) ++r0;
            if (pj < p1) ++r1;
        }
        if ((unsigned)t < C && r0 == kk - 1)        sh[1] = p0;
        if ((unsigned)(t + 64) < C && r1 == kk - 1) sh[1] = p1;
    }
    __syncthreads();
    pstar = sh[1];
    __syncthreads();
}

// Exact, slow, practically-unreachable fallback: full radix with recompute.
template <class FK>
__device__ void fallback_radix(const FK& fullkey, unsigned* hist, volatile unsigned* sh,
                               int k, unsigned& vstar, unsigned& pstar)
{
    const int t = threadIdx.x;
    int kk = k; unsigned prefix = 0;
    for (int pass = 0; pass < 4; ++pass) {
        const int shift = 24 - pass * 8;
        if (t < 256) hist[t] = 0;
        __syncthreads();
        for (int j = 0; j < PER_T; ++j) {
            const unsigned p = (unsigned)(j * NT + t);
            const unsigned v = fullkey(p);
            bool in = (pass == 0) || ((v >> (shift + 8)) == prefix);
            if (in) atomicAdd(&hist[(v >> shift) & 255u], 1u);
        }
        __syncthreads();
        unsigned b; hist_pick(hist, sh, 256, &kk, &b);
        prefix = (prefix << 8) | b;
    }
    vstar = prefix;
    unsigned ipref = 0;
    for (int pass = 0; pass < 2; ++pass) {
        const int shift = 7 - pass * 7;
        if (t < 128) hist[t] = 0;
        __syncthreads();
        for (int j = 0; j < PER_T; ++j) {
            const unsigned p = (unsigned)(j * NT + t);
            bool in = (fullkey(p) == vstar);
            if (in && pass != 0) in = ((p >> (shift + 7)) == ipref);
            if (in) atomicAdd(&hist[(p >> shift) & 127u], 1u);
        }
        __syncthreads();
        unsigned b; hist_pick(hist, sh, 128, &kk, &b);
        ipref = (ipref << 7) | b;
    }
    pstar = ipref;
}

// Main select: caller filled keys16[] (top 16 bits) and hist[4096] (top-12 hist).
template <class FK>
__device__ void select16(const FK& fullkey, const unsigned short* keys16,
                         unsigned* hist, volatile unsigned* sh,
                         unsigned short* cand, unsigned* ccnt, int k,
                         unsigned& vstar, unsigned& pstar)
{
    const int t = threadIdx.x;
    int kk = k;
    unsigned b0; pick_bpt<4>(hist, sh, &kk, &b0);

    if (t == 0) *ccnt = 0;
    __syncthreads();
    #pragma unroll 4
    for (int j = 0; j < PER_T; ++j) {
        const unsigned p = (unsigned)(j * NT + t);
        if ((unsigned)(keys16[p] >> 4) == b0) {
            const unsigned pos = atomicAdd(ccnt, 1u);
            if (pos < CAP2) cand[pos] = (unsigned short)p;
        }
    }
    __syncthreads();
    unsigned C = *ccnt;
    __syncthreads();
    if (C <= CAP2) {
        const Lvl lvA[2] = { {10, 1024}, {0, 1024} };
        narrow_cand(fullkey, cand, ccnt, hist, sh, C, kk, b0 << 20, lvA, 2, vstar, pstar);
        return;
    }
    // rare: refine by keys16 low nibble (light scan)
    if (t < 16) hist[t] = 0;
    __syncthreads();
    #pragma unroll 4
    for (int j = 0; j < PER_T; ++j) {
        const unsigned p = (unsigned)(j * NT + t);
        const unsigned k16 = keys16[p];
        if ((k16 >> 4) == b0) atomicAdd(&hist[k16 & 15u], 1u);
    }
    __syncthreads();
    unsigned b1; hist_pick(hist, sh, 16, &kk, &b1);
    const unsigned pref16 = (b0 << 4) | b1;
    if (t == 0) *ccnt = 0;
    __syncthreads();
    #pragma unroll 4
    for (int j = 0; j < PER_T; ++j) {
        const unsigned p = (unsigned)(j * NT + t);
        if ((unsigned)keys16[p] == pref16) {
            const unsigned pos = atomicAdd(ccnt, 1u);
            if (pos < CAP2) cand[pos] = (unsigned short)p;
        }
    }
    __syncthreads();
    C = *ccnt;
    __syncthreads();
    if (C <= CAP2) {
        const Lvl lvB[2] = { {8, 256}, {0, 256} };
        narrow_cand(fullkey, cand, ccnt, hist, sh, C, kk, pref16 << 16, lvB, 2, vstar, pstar);
        return;
    }
    fallback_radix(fullkey, hist, sh, k, vstar, pstar);
}

#define DECL_SHARED                                         \
    __shared__ unsigned short keys16[PP];                   \
    __shared__ unsigned hist[4096];                         \
    __shared__ unsigned sh_[24];                            \
    __shared__ unsigned ccnt_s;                             \
    __shared__ unsigned short cand[CAP2];                   \
    volatile unsigned* sh = (volatile unsigned*)sh_;

// ---- kernel A: 10 smallest rand_centers per row -> ws clist; clears uni ----
extern "C" __global__ void __launch_bounds__(NT, 8)
bpm_centers(const float* __restrict__ rand_centers, unsigned* __restrict__ ws_cl,
            unsigned* __restrict__ uni)
{
    DECL_SHARED
    __shared__ unsigned clist[16];
    __shared__ unsigned pcnt;

    const int bm = blockIdx.x;
    const int t  = threadIdx.x;
    if (t < UNI_WPR) uni[bm * UNI_WPR + t] = 0u;   // clear union bitmap

    const float* rcrow = rand_centers + (size_t)bm * PP;
    auto fullkey = [rcrow](unsigned p) -> unsigned { return mapf(rcrow[p]); };

    #pragma unroll
    for (int i = 0; i < 4; ++i) hist[t * 4 + i] = 0;
    if (t == 0) pcnt = 0;
    __syncthreads();
    #pragma unroll
    for (int j = 0; j < KG_IT; ++j) {
        const int q = j * (NT * 4) + t * 4;
        const float4 v = *(const float4*)(rcrow + q);
        const unsigned k0 = mapf(v.x), k1 = mapf(v.y), k2 = mapf(v.z), k3 = mapf(v.w);
        *(ushort4*)(keys16 + q) = make_ushort4((unsigned short)(k0 >> 16),
                                               (unsigned short)(k1 >> 16),
                                               (unsigned short)(k2 >> 16),
                                               (unsigned short)(k3 >> 16));
        atomicAdd(&hist[k0 >> 20], 1u);
        atomicAdd(&hist[k1 >> 20], 1u);
        atomicAdd(&hist[k2 >> 20], 1u);
        atomicAdd(&hist[k3 >> 20], 1u);
    }
    __syncthreads();

    unsigned vs, ps;
    select16(fullkey, keys16, hist, sh, cand, &ccnt_s, NC, vs, ps);
    const unsigned vs16 = vs >> 16;

    #pragma unroll 4
    for (int j = 0; j < PER_T; ++j) {
        const unsigned p = (unsigned)(j * NT + t);
        const unsigned k16 = keys16[p];
        bool sel = false;
        if (k16 < vs16) sel = true;
        else if (k16 == vs16) {
            const unsigned v = fullkey(p);
            sel = (v < vs) || (v == vs && p <= ps);
        }
        if (sel) clist[atomicAdd(&pcnt, 1u)] = p;   // order irrelevant (set union)
    }
    __syncthreads();
    if (t < NC) ws_cl[bm * 16 + t] = clist[t];
}

// ---- kernel B: one block per (row, center): 819-NN -> atomicOr bitmap ----
// 1D grid 1280, XCD-swizzled: all 10 blocks of a row share bid%8 -> same XCD
// L2 caches the row (196KB; 16 rows/XCD = 3.1MB < 4MB).
extern "C" __global__ void __launch_bounds__(NT, 8)
bpm_knn(const float* __restrict__ centers, const unsigned* __restrict__ ws_cl,
        unsigned* __restrict__ uni)
{
    DECL_SHARED
    const int bid   = blockIdx.x;
    const int inner = bid >> 3;                   // [0,160)
    const int bm    = (inner / NC) * 8 + (bid & 7);
    const int c     = inner % NC;
    const int b     = bm >> 1;
    const int t     = threadIdx.x;
    const float* crow = centers + (size_t)b * PP * 3;

    const int ci = (int)ws_cl[bm * 16 + c];
    const float sx = crow[ci * 3 + 0];
    const float sy = crow[ci * 3 + 1];
    const float sz = crow[ci * 3 + 2];
    const float s2 = __fadd_rn(__fadd_rn(__fmul_rn(sx, sx), __fmul_rn(sy, sy)),
                               __fmul_rn(sz, sz));
    auto fullkey = [crow, sx, sy, sz, s2](unsigned p) -> unsigned {
        const float cx = crow[3 * p + 0], cy = crow[3 * p + 1], cz = crow[3 * p + 2];
        return mapf(d2_core(cx, cy, cz, sx, sy, sz, s2));
    };

    #pragma unroll
    for (int i = 0; i < 4; ++i) hist[t * 4 + i] = 0;
    __syncthreads();
    #pragma unroll
    for (int j = 0; j < KG_IT; ++j) {
        const int q = j * (NT * 4) + t * 4;       // 4 points, 48B = 3x float4
        const float4* cp4 = (const float4*)(crow + 3 * q);
        const float4 A = cp4[0], Bv = cp4[1], Cv = cp4[2];
        const unsigned k0 = mapf(d2_core(A.x,  A.y,  A.z,  sx, sy, sz, s2));
        const unsigned k1 = mapf(d2_core(A.w,  Bv.x, Bv.y, sx, sy, sz, s2));
        const unsigned k2 = mapf(d2_core(Bv.z, Bv.w, Cv.x, sx, sy, sz, s2));
        const unsigned k3 = mapf(d2_core(Cv.y, Cv.z, Cv.w, sx, sy, sz, s2));
        *(ushort4*)(keys16 + q) = make_ushort4((unsigned short)(k0 >> 16),
                                               (unsigned short)(k1 >> 16),
                                               (unsigned short)(k2 >> 16),
                                               (unsigned short)(k3 >> 16));
        atomicAdd(&hist[k0 >> 20], 1u);
        atomicAdd(&hist[k1 >> 20], 1u);
        atomicAdd(&hist[k2 >> 20], 1u);
        atomicAdd(&hist[k3 >> 20], 1u);
    }
    __syncthreads();

    unsigned vs, ps;
    select16(fullkey, keys16, hist, sh, cand, &ccnt_s, KNN, vs, ps);
    const unsigned vs16 = vs >> 16;

    unsigned* urow = uni + (size_t)bm * UNI_WPR;
    #pragma unroll 4
    for (int j = 0; j < PER_T; ++j) {
        const unsigned p = (unsigned)(j * NT + t);
        const unsigned k16 = keys16[p];
        bool sel = false;
        if (k16 < vs16) sel = true;
        else if (k16 == vs16) {
            const unsigned v = fullkey(p);
            sel = (v < vs) || (v == vs && p <= ps);
        }
        const unsigned long long bmask = __ballot(sel);
        if ((t & 63) == 0 && bmask) {
            const int wbase = (int)(p >> 5);
            const unsigned lo = (unsigned)bmask;
            const unsigned hi = (unsigned)(bmask >> 32);
            if (lo) atomicOr(&urow[wbase], lo);
            if (hi) atomicOr(&urow[wbase + 1], hi);
        }
    }
}

// ---- kernel C: flip by union bit, select 9830, write int mask ----
extern "C" __global__ void __launch_bounds__(NT, 8)
bpm_final(const float* __restrict__ rand_mask, const unsigned* __restrict__ uni,
          int* __restrict__ out)
{
    DECL_SHARED
    const int bm = blockIdx.x;
    const int t  = threadIdx.x;
    const float* rmrow = rand_mask + (size_t)bm * PP;
    const unsigned* urow = uni + (size_t)bm * UNI_WPR;

    auto fullkey = [rmrow, urow](unsigned p) -> unsigned {
        const float r = rmrow[p];
        const bool inb = (urow[p >> 5] >> (p & 31)) & 1u;
        return mapf(inb ? -r : r);
    };

    #pragma unroll
    for (int i = 0; i < 4; ++i) hist[t * 4 + i] = 0;
    __syncthreads();
    #pragma unroll
    for (int j = 0; j < KG_IT; ++j) {
        const int q = j * (NT * 4) + t * 4;
        const float4 v = *(const float4*)(rmrow + q);
        const unsigned w = urow[q >> 5];           // 4 bits in same word (q%4==0)
        const unsigned k0 = mapf(((w >> ((q + 0) & 31)) & 1u) ? -v.x : v.x);
        const unsigned k1 = mapf(((w >> ((q + 1) & 31)) & 1u) ? -v.y : v.y);
        const unsigned k2 = mapf(((w >> ((q + 2) & 31)) & 1u) ? -v.z : v.z);
        const unsigned k3 = mapf(((w >> ((q + 3) & 31)) & 1u) ? -v.w : v.w);
        *(ushort4*)(keys16 + q) = make_ushort4((unsigned short)(k0 >> 16),
                                               (unsigned short)(k1 >> 16),
                                               (unsigned short)(k2 >> 16),
                                               (unsigned short)(k3 >> 16));
        atomicAdd(&hist[k0 >> 20], 1u);
        atomicAdd(&hist[k1 >> 20], 1u);
        atomicAdd(&hist[k2 >> 20], 1u);
        atomicAdd(&hist[k3 >> 20], 1u);
    }
    __syncthreads();

    unsigned vs, ps;
    select16(fullkey, keys16, hist, sh, cand, &ccnt_s, NMASK, vs, ps);
    const unsigned vs16 = vs >> 16;

    int* orow = out + (size_t)bm * PP;
    #pragma unroll 4
    for (int j = 0; j < PER_T; ++j) {
        const unsigned p = (unsigned)(j * NT + t);
        const unsigned k16 = keys16[p];
        bool sel = false;
        if (k16 < vs16) sel = true;
        else if (k16 == vs16) {
            const unsigned v = fullkey(p);
            sel = (v < vs) || (v == vs && p <= ps);
        }
        orow[p] = sel ? 1 : 0;
    }
}

extern "C" void kernel_launch(void* const* d_in, const int* in_sizes, int n_in,
                              void* d_out, int out_size, void* d_ws, size_t ws_size,
                              hipStream_t stream)
{
    (void)in_sizes; (void)n_in; (void)out_size; (void)ws_size;
    const float* centers      = (const float*)d_in[0];
    const float* rand_centers = (const float*)d_in[1];
    const float* rand_mask    = (const float*)d_in[2];
    int* out = (int*)d_out;

    unsigned* ws_cl = (unsigned*)d_ws;          // ws_size >= 264KB verified r4-r8
    unsigned* uni   = ws_cl + WS_CL_U32;

    bpm_centers<<<dim3(NROW), dim3(NT), 0, stream>>>(rand_centers, ws_cl, uni);
    bpm_knn<<<dim3(NROW * NC), dim3(NT), 0, stream>>>(centers, ws_cl, uni);
    bpm_final<<<dim3(NROW), dim3(NT), 0, stream>>>(rand_mask, uni, out);
}